// Round 2
// baseline (2430.516 us; speedup 1.0000x reference)
//
#include <hip/hip_runtime.h>
#include <hip/hip_bf16.h>
#include <math.h>

// ---------------- geometry ----------------
#define BATCH   2
#define LQ      4096            // seqlen
#define RTOT    8192            // BATCH*LQ rows
#define DM      1024            // d_model
#define DI      2048            // d_inner
#define NH      32              // heads
#define HD      64              // head dim p
#define DS      128             // d_state n
#define CH      256             // chunk
#define NC      16              // chunks per seq
#define XBC_C   2304            // conv channels
#define ZX_C    4384            // in_proj output cols
#define EPS     1e-5f

typedef __hip_bfloat16 bf16;

// ---------------- block reduce ----------------
__device__ __forceinline__ float block_reduce_sum(float v) {
    __shared__ float sred[8];
    int lane = threadIdx.x & 63, w = threadIdx.x >> 6;
#pragma unroll
    for (int off = 32; off > 0; off >>= 1) v += __shfl_down(v, off, 64);
    if (lane == 0) sred[w] = v;
    __syncthreads();
    float t = (threadIdx.x < (int)(blockDim.x >> 6)) ? sred[threadIdx.x] : 0.f;
    if (w == 0) {
#pragma unroll
        for (int off = 4; off > 0; off >>= 1) t += __shfl_down(t, off, 64);
        if (lane == 0) sred[0] = t;
    }
    __syncthreads();
    return sred[0];
}

// ---------------- K1: res = hid + residual; h = rmsnorm(res)*w ----------------
__global__ __launch_bounds__(256) void add_rmsnorm_kernel(
    const float* __restrict__ hid, const float* __restrict__ resid,
    const float* __restrict__ w, float* __restrict__ res_out,
    float* __restrict__ h_out) {
    int r = blockIdx.x;
    int tid = threadIdx.x;
    size_t base = (size_t)r * DM;
    float4 hv = *(const float4*)&hid[base + tid * 4];
    float4 rv = *(const float4*)&resid[base + tid * 4];
    float4 s = {hv.x + rv.x, hv.y + rv.y, hv.z + rv.z, hv.w + rv.w};
    *(float4*)&res_out[base + tid * 4] = s;
    float ss = s.x * s.x + s.y * s.y + s.z * s.z + s.w * s.w;
    ss = block_reduce_sum(ss);
    float scale = rsqrtf(ss / (float)DM + EPS);
    float4 wv = *(const float4*)&w[tid * 4];
    float4 o = {s.x * scale * wv.x, s.y * scale * wv.y,
                s.z * scale * wv.z, s.w * scale * wv.w};
    *(float4*)&h_out[base + tid * 4] = o;
}

// ---------------- GEMM1: C_bf16[M,N] = A[M,K] @ B[K,N]; dt cols also fp32 ----
__global__ __launch_bounds__(256) void gemm1_kernel(
    const float* __restrict__ A, const float* __restrict__ B,
    bf16* __restrict__ C, float* __restrict__ dtraw,
    int M, int N, int K) {
    __shared__ float As[16][68];
    __shared__ float Bs[16][68];
    int tid = threadIdx.x;
    int tx = tid & 15, ty = tid >> 4;
    int m0 = blockIdx.y << 6, n0 = blockIdx.x << 6;
    float acc[4][4] = {};
    for (int k0 = 0; k0 < K; k0 += 16) {
        int aj = tid & 15;
        int ai = tid >> 4;
#pragma unroll
        for (int r = 0; r < 4; ++r)
            As[aj][ai + r * 16] = A[(size_t)(m0 + ai + r * 16) * K + k0 + aj];
        int bj = tid & 63;
        int bi = tid >> 6;
        int nn = n0 + bj;
#pragma unroll
        for (int r = 0; r < 4; ++r)
            Bs[bi + r * 4][bj] = (nn < N) ? B[(size_t)(k0 + bi + r * 4) * N + nn] : 0.f;
        __syncthreads();
#pragma unroll
        for (int k = 0; k < 16; ++k) {
            float4 av = *(const float4*)&As[k][ty * 4];
            float4 bv = *(const float4*)&Bs[k][tx * 4];
            float a[4] = {av.x, av.y, av.z, av.w};
            float b[4] = {bv.x, bv.y, bv.z, bv.w};
#pragma unroll
            for (int i = 0; i < 4; ++i)
#pragma unroll
                for (int j = 0; j < 4; ++j)
                    acc[i][j] = fmaf(a[i], b[j], acc[i][j]);
        }
        __syncthreads();
    }
#pragma unroll
    for (int i = 0; i < 4; ++i) {
        int m = m0 + ty * 4 + i;
#pragma unroll
        for (int j = 0; j < 4; ++j) {
            int n = n0 + tx * 4 + j;
            if (n < N) {
                C[(size_t)m * N + n] = __float2bfloat16(acc[i][j]);
                if (n >= 4352) dtraw[(size_t)m * 32 + (n - 4352)] = acc[i][j];
            }
        }
    }
}

// ---------------- GEMM2: C_f32[M,N] = A_bf16[M,K](lda) @ B[K,N] --------------
__global__ __launch_bounds__(256) void gemm2_kernel(
    const bf16* __restrict__ A, int lda, const float* __restrict__ B,
    float* __restrict__ C, int M, int N, int K) {
    __shared__ float As[16][68];
    __shared__ float Bs[16][68];
    int tid = threadIdx.x;
    int tx = tid & 15, ty = tid >> 4;
    int m0 = blockIdx.y << 6, n0 = blockIdx.x << 6;
    float acc[4][4] = {};
    for (int k0 = 0; k0 < K; k0 += 16) {
        int aj = tid & 15;
        int ai = tid >> 4;
#pragma unroll
        for (int r = 0; r < 4; ++r)
            As[aj][ai + r * 16] =
                __bfloat162float(A[(size_t)(m0 + ai + r * 16) * lda + k0 + aj]);
        int bj = tid & 63;
        int bi = tid >> 6;
        int nn = n0 + bj;
#pragma unroll
        for (int r = 0; r < 4; ++r)
            Bs[bi + r * 4][bj] = (nn < N) ? B[(size_t)(k0 + bi + r * 4) * N + nn] : 0.f;
        __syncthreads();
#pragma unroll
        for (int k = 0; k < 16; ++k) {
            float4 av = *(const float4*)&As[k][ty * 4];
            float4 bv = *(const float4*)&Bs[k][tx * 4];
            float a[4] = {av.x, av.y, av.z, av.w};
            float b[4] = {bv.x, bv.y, bv.z, bv.w};
#pragma unroll
            for (int i = 0; i < 4; ++i)
#pragma unroll
                for (int j = 0; j < 4; ++j)
                    acc[i][j] = fmaf(a[i], b[j], acc[i][j]);
        }
        __syncthreads();
    }
#pragma unroll
    for (int i = 0; i < 4; ++i) {
        int m = m0 + ty * 4 + i;
#pragma unroll
        for (int j = 0; j < 4; ++j) {
            int n = n0 + tx * 4 + j;
            if (n < N) C[(size_t)m * N + n] = acc[i][j];
        }
    }
}

// ---------------- K3: depthwise causal conv(4) + bias + SiLU ----------------
__global__ __launch_bounds__(256) void conv_silu_kernel(
    const bf16* __restrict__ zx, const float* __restrict__ conv_w,
    const float* __restrict__ conv_b, bf16* __restrict__ xBC) {
    int idx = blockIdx.x * 256 + threadIdx.x;
    int r = idx / XBC_C;
    int c = idx - r * XBC_C;
    int b = r >> 12, l = r & (LQ - 1);
    float acc = conv_b[c];
#pragma unroll
    for (int k = 0; k < 4; ++k) {
        int t = l - 3 + k;
        if (t >= 0)
            acc = fmaf(conv_w[k * XBC_C + c],
                       __bfloat162float(zx[(size_t)(b * LQ + t) * ZX_C + DI + c]), acc);
    }
    xBC[(size_t)r * XBC_C + c] = __float2bfloat16(acc / (1.f + __expf(-acc)));
}

// ---------------- K3b: dt = softplus(dt_raw + bias); chunk cumsum of dt*A ----
__global__ __launch_bounds__(256) void dt_scan_kernel(
    const float* __restrict__ dtraw, const float* __restrict__ dt_bias,
    const float* __restrict__ A_log, float* __restrict__ dt_bh,
    float* __restrict__ Acum_bh) {
    __shared__ float sA[256];
    int bid = blockIdx.x;                       // (b,h,c)
    int c = bid & 15, h = (bid >> 4) & 31, b = bid >> 9;
    int tid = threadIdx.x;
    int l = c * CH + tid;
    int r = b * LQ + l;
    float v = dtraw[(size_t)r * 32 + h] + dt_bias[h];
    float dt = (v > 20.f) ? v : log1pf(expf(v));
    float A = -expf(A_log[h]);
    sA[tid] = dt * A;
    __syncthreads();
    for (int off = 1; off < 256; off <<= 1) {
        float t = (tid >= off) ? sA[tid - off] : 0.f;
        __syncthreads();
        sA[tid] += t;
        __syncthreads();
    }
    size_t o = (size_t)(b * NH + h) * LQ + l;
    dt_bh[o] = dt;
    Acum_bh[o] = sA[tid];
}

// ---------------- K4a: states[p,n] = sum_l B[l,n]*dt[l]*decay[l]*x[l,p] ------
__global__ __launch_bounds__(256) void states_kernel(
    const bf16* __restrict__ xBC, const float* __restrict__ dt_bh,
    const float* __restrict__ Acum_bh, float* __restrict__ states) {
    __shared__ float Bt[64][129];
    __shared__ float Xt[64][65];
    __shared__ float sc[64];
    int bid = blockIdx.x;                       // (b,h,c)
    int c = bid & 15, h = (bid >> 4) & 31, b = bid >> 9;
    int bh = b * NH + h;
    int tid = threadIdx.x;
    int tx = tid & 15, ty = tid >> 4;
    float acc[4][8] = {};
    float Alast = Acum_bh[(size_t)bh * LQ + c * CH + (CH - 1)];
    for (int lt = 0; lt < 4; ++lt) {
        int s0 = lt * 64;
        int rs0 = b * LQ + c * CH + s0;
        if (tid < 64) {
            float ac = Acum_bh[(size_t)bh * LQ + c * CH + s0 + tid];
            float dtv = dt_bh[(size_t)bh * LQ + c * CH + s0 + tid];
            sc[tid] = dtv * __expf(Alast - ac);
        }
        {
            int n = tid & 127, sr = tid >> 7;
#pragma unroll
            for (int r = 0; r < 32; ++r)
                Bt[sr + r * 2][n] =
                    __bfloat162float(xBC[(size_t)(rs0 + sr + r * 2) * XBC_C + DI + n]);
        }
        {
            int p = tid & 63, sr = tid >> 6;
#pragma unroll
            for (int r = 0; r < 16; ++r)
                Xt[sr + r * 4][p] =
                    __bfloat162float(xBC[(size_t)(rs0 + sr + r * 4) * XBC_C + h * HD + p]);
        }
        __syncthreads();
#pragma unroll 4
        for (int k = 0; k < 64; ++k) {
            float s = sc[k];
            float a[4], bb[8];
#pragma unroll
            for (int q = 0; q < 4; ++q) a[q] = Xt[k][ty * 4 + q] * s;
#pragma unroll
            for (int q = 0; q < 8; ++q) bb[q] = Bt[k][tx * 8 + q];
#pragma unroll
            for (int i = 0; i < 4; ++i)
#pragma unroll
                for (int j = 0; j < 8; ++j)
                    acc[i][j] = fmaf(a[i], bb[j], acc[i][j]);
        }
        __syncthreads();
    }
    size_t base = (size_t)(bh * NC + c) * HD * DS;
#pragma unroll
    for (int i = 0; i < 4; ++i) {
        int p = ty * 4 + i;
#pragma unroll
        for (int j = 0; j < 8; ++j) {
            int n = tx * 8 + j;
            states[base + (size_t)p * DS + n] = acc[i][j];
        }
    }
}

// ---------------- K5: inter-chunk scan, in place ------------------------------
__global__ __launch_bounds__(256) void chunk_scan_kernel(
    float* __restrict__ states, const float* __restrict__ Acum_bh) {
    int bh = blockIdx.x;
    int tid = threadIdx.x;
    float carry[32];
#pragma unroll
    for (int j = 0; j < 32; ++j) carry[j] = 0.f;
    for (int c = 0; c < NC; ++c) {
        float dec = __expf(Acum_bh[(size_t)bh * LQ + c * CH + (CH - 1)]);
        size_t base = (size_t)(bh * NC + c) * (HD * DS);
#pragma unroll
        for (int j = 0; j < 32; ++j) {
            size_t idx = base + tid + j * 256;
            float tmp = states[idx];
            states[idx] = carry[j];
            carry[j] = carry[j] * dec + tmp;
        }
    }
}

// ---------------- K4b: Y = diag + off + D*x; bf16 out, strided ZX_C ----------
__global__ __launch_bounds__(256) void y_kernel(
    const bf16* __restrict__ xBC, const float* __restrict__ dt_bh,
    const float* __restrict__ Acum_bh, const float* __restrict__ prev,
    const float* __restrict__ Dvec, bf16* __restrict__ yout /* zx+2048, lda ZX_C */) {
    __shared__ float Cl[64][129];
    __shared__ float Wbuf[64 * 129];  // W tile; St[64][65] aliases the front
    __shared__ bf16 Xs[64][66];
    __shared__ float AclS[64];
    __shared__ float AsS[64];
#define Wm(i, j)  Wbuf[(i) * 129 + (j)]
#define Stm(i, j) Wbuf[(i) * 65 + (j)]
    int bid = blockIdx.x;                       // (b,h,c,lt)
    int lt = bid & 3, c = (bid >> 2) & 15, h = (bid >> 6) & 31, b = bid >> 11;
    int tid = threadIdx.x;
    int tx = tid & 15, ty = tid >> 4;
    int bh = b * NH + h;
    int l0 = lt * 64;
    int r0 = b * LQ + c * CH + l0;
    {
        int n = tid & 127, lr = tid >> 7;
#pragma unroll
        for (int r = 0; r < 32; ++r)
            Cl[lr + r * 2][n] =
                __bfloat162float(xBC[(size_t)(r0 + lr + r * 2) * XBC_C + DI + DS + n]);
    }
    if (tid < 64) AclS[tid] = Acum_bh[(size_t)bh * LQ + c * CH + l0 + tid];
    {
        int n = tid & 127, pr = tid >> 7;
        size_t base = (size_t)(bh * NC + c) * HD * DS;
#pragma unroll
        for (int r = 0; r < 32; ++r)
            Wm(pr + r * 2, n) = prev[base + (size_t)(pr + r * 2) * DS + n];
    }
    __syncthreads();
    float accoff[4][4] = {};
#pragma unroll 4
    for (int k = 0; k < 128; ++k) {
        float a[4], bb[4];
#pragma unroll
        for (int q = 0; q < 4; ++q) a[q] = Cl[ty * 4 + q][k];
#pragma unroll
        for (int q = 0; q < 4; ++q) bb[q] = Wm(tx * 4 + q, k);
#pragma unroll
        for (int i = 0; i < 4; ++i)
#pragma unroll
            for (int j = 0; j < 4; ++j)
                accoff[i][j] = fmaf(a[i], bb[j], accoff[i][j]);
    }
    __syncthreads();
    float acc[4][4] = {};
    for (int st = 0; st <= lt; ++st) {
        int s0 = st * 64;
        int rs0 = b * LQ + c * CH + s0;
        {
            int n = tid & 127, sr = tid >> 7;
#pragma unroll
            for (int r = 0; r < 32; ++r)
                Wm(sr + r * 2, n) =
                    __bfloat162float(xBC[(size_t)(rs0 + sr + r * 2) * XBC_C + DI + n]);
        }
        {
            int p = tid & 63, sr = tid >> 6;
#pragma unroll
            for (int r = 0; r < 16; ++r) {
                int s = sr + r * 4;
                float dtv = dt_bh[(size_t)bh * LQ + c * CH + s0 + s];
                float xv = __bfloat162float(xBC[(size_t)(rs0 + s) * XBC_C + h * HD + p]);
                Xs[s][p] = __float2bfloat16(xv * dtv);
            }
        }
        if (tid < 64) AsS[tid] = Acum_bh[(size_t)bh * LQ + c * CH + s0 + tid];
        __syncthreads();
        float sreg[4][4] = {};
#pragma unroll 4
        for (int k = 0; k < 128; ++k) {
            float a[4], bb[4];
#pragma unroll
            for (int q = 0; q < 4; ++q) a[q] = Cl[ty * 4 + q][k];
#pragma unroll
            for (int q = 0; q < 4; ++q) bb[q] = Wm(tx * 4 + q, k);
#pragma unroll
            for (int i = 0; i < 4; ++i)
#pragma unroll
                for (int j = 0; j < 4; ++j)
                    sreg[i][j] = fmaf(a[i], bb[j], sreg[i][j]);
        }
        __syncthreads();   // all W reads done before St (aliased) is written
#pragma unroll
        for (int i = 0; i < 4; ++i) {
            int lg = l0 + ty * 4 + i;
            float al = AclS[ty * 4 + i];
#pragma unroll
            for (int j = 0; j < 4; ++j) {
                int sg = s0 + tx * 4 + j;
                float v = (sg <= lg) ? sreg[i][j] * __expf(al - AsS[tx * 4 + j]) : 0.f;
                Stm(ty * 4 + i, tx * 4 + j) = v;
            }
        }
        __syncthreads();
#pragma unroll 4
        for (int k = 0; k < 64; ++k) {
            float a[4], bb[4];
#pragma unroll
            for (int q = 0; q < 4; ++q) a[q] = Stm(ty * 4 + q, k);
#pragma unroll
            for (int q = 0; q < 4; ++q) bb[q] = __bfloat162float(Xs[k][tx * 4 + q]);
#pragma unroll
            for (int i = 0; i < 4; ++i)
#pragma unroll
                for (int j = 0; j < 4; ++j)
                    acc[i][j] = fmaf(a[i], bb[j], acc[i][j]);
        }
        __syncthreads();
    }
    float Dh = Dvec[h];
#pragma unroll
    for (int i = 0; i < 4; ++i) {
        int l = ty * 4 + i;
        float e = __expf(AclS[l]);
        int gr = r0 + l;
        const bf16* xp = &xBC[(size_t)gr * XBC_C + h * HD + tx * 4];
        float ov[4];
#pragma unroll
        for (int j = 0; j < 4; ++j)
            ov[j] = acc[i][j] + e * accoff[i][j] + Dh * __bfloat162float(xp[j]);
        bf16* yp = yout + (size_t)gr * ZX_C + h * HD + tx * 4;
        __hip_bfloat162 p0, p1;
        p0.x = __float2bfloat16(ov[0]); p0.y = __float2bfloat16(ov[1]);
        p1.x = __float2bfloat16(ov[2]); p1.y = __float2bfloat16(ov[3]);
        *(__hip_bfloat162*)yp = p0;
        *(__hip_bfloat162*)(yp + 2) = p1;
    }
#undef Wm
#undef Stm
}

// ---------------- K6: y = rmsnorm(y * silu(z)) * gw, in place (strided) ------
__global__ __launch_bounds__(256) void gate_norm_kernel(
    const bf16* __restrict__ zx, const float* __restrict__ gw,
    bf16* __restrict__ y /* zx+2048, lda ZX_C */) {
    int r = blockIdx.x;
    int tid = threadIdx.x;
    float v[8];
    float ss = 0.f;
#pragma unroll
    for (int q = 0; q < 8; ++q) {
        int i = tid + q * 256;
        float z = __bfloat162float(zx[(size_t)r * ZX_C + i]);
        float val = __bfloat162float(y[(size_t)r * ZX_C + i]) * (z / (1.f + __expf(-z)));
        v[q] = val;
        ss += val * val;
    }
    ss = block_reduce_sum(ss);
    float scale = rsqrtf(ss / (float)DI + EPS);
#pragma unroll
    for (int q = 0; q < 8; ++q) {
        int i = tid + q * 256;
        y[(size_t)r * ZX_C + i] = __float2bfloat16(v[q] * scale * gw[i]);
    }
}

// ---------------- launch ----------------
extern "C" void kernel_launch(void* const* d_in, const int* in_sizes, int n_in,
                              void* d_out, int out_size, void* d_ws, size_t ws_size,
                              hipStream_t stream) {
    const float* hid      = (const float*)d_in[0];
    const float* resid    = (const float*)d_in[1];
    const float* norm_w   = (const float*)d_in[2];
    const float* in_proj  = (const float*)d_in[3];
    const float* conv_w   = (const float*)d_in[4];
    const float* conv_b   = (const float*)d_in[5];
    const float* dt_bias  = (const float*)d_in[6];
    const float* A_log    = (const float*)d_in[7];
    const float* Dvec     = (const float*)d_in[8];
    const float* gate_w   = (const float*)d_in[9];
    const float* out_proj = (const float*)d_in[10];

    float* out_p   = (float*)d_out;                  // [8192,1024] f32
    float* res_out = out_p + (size_t)RTOT * DM;      // [8192,1024] f32
    // h_norm lives in the out region (dead after GEMM1); states reuses the
    // same region afterwards (exactly 8192*1024 f32), dead before GEMM2.
    float* h_norm  = out_p;
    float* states  = out_p;

    // workspace: ~113 MB total
    char* wsb = (char*)d_ws;
    bf16*  zx      = (bf16*)wsb;  wsb += (size_t)RTOT * ZX_C * sizeof(bf16);   // 71.8 MB
    bf16*  xBC     = (bf16*)wsb;  wsb += (size_t)RTOT * XBC_C * sizeof(bf16);  // 37.7 MB
    float* dtraw   = (float*)wsb; wsb += (size_t)RTOT * 32 * sizeof(float);    //  1.0 MB
    float* dt_bh   = (float*)wsb; wsb += (size_t)BATCH * NH * LQ * sizeof(float);
    float* Acum_bh = (float*)wsb; wsb += (size_t)BATCH * NH * LQ * sizeof(float);

    add_rmsnorm_kernel<<<RTOT, 256, 0, stream>>>(hid, resid, norm_w, res_out, h_norm);
    gemm1_kernel<<<dim3((ZX_C + 63) / 64, RTOT / 64), 256, 0, stream>>>(
        h_norm, in_proj, zx, dtraw, RTOT, ZX_C, DM);
    conv_silu_kernel<<<(RTOT * XBC_C) / 256, 256, 0, stream>>>(
        zx, conv_w, conv_b, xBC);
    dt_scan_kernel<<<BATCH * NH * NC, 256, 0, stream>>>(
        dtraw, dt_bias, A_log, dt_bh, Acum_bh);
    states_kernel<<<BATCH * NH * NC, 256, 0, stream>>>(
        xBC, dt_bh, Acum_bh, states);
    chunk_scan_kernel<<<BATCH * NH, 256, 0, stream>>>(states, Acum_bh);
    y_kernel<<<BATCH * NH * NC * 4, 256, 0, stream>>>(
        xBC, dt_bh, Acum_bh, states, Dvec, zx + DI);
    gate_norm_kernel<<<RTOT, 256, 0, stream>>>(zx, gate_w, zx + DI);
    gemm2_kernel<<<dim3(DM / 64, RTOT / 64), 256, 0, stream>>>(
        zx + DI, ZX_C, out_proj, out_p, RTOT, DM, DI);
}

// Round 3
// 1129.726 us; speedup vs baseline: 2.1514x; 2.1514x over previous
//
#include <hip/hip_runtime.h>
#include <hip/hip_bf16.h>
#include <math.h>

// ---------------- geometry ----------------
#define BATCH   2
#define LQ      4096            // seqlen
#define RTOT    8192            // BATCH*LQ rows
#define DM      1024            // d_model
#define DI      2048            // d_inner
#define NH      32              // heads
#define HD      64              // head dim p
#define DS      128             // d_state n
#define CH      256             // chunk
#define NC      16              // chunks per seq
#define XBC_C   2304            // conv channels
#define ZX_C    4384            // in_proj output cols
#define NP1     4480            // padded N for gemm1 B^T (35*128)
#define EPS     1e-5f

typedef __hip_bfloat16 bf16;
typedef __bf16 bf16x8v __attribute__((ext_vector_type(8)));
typedef float f32x4v __attribute__((ext_vector_type(4)));

// ---------------- block reduce ----------------
__device__ __forceinline__ float block_reduce_sum(float v) {
    __shared__ float sred[8];
    int lane = threadIdx.x & 63, w = threadIdx.x >> 6;
#pragma unroll
    for (int off = 32; off > 0; off >>= 1) v += __shfl_down(v, off, 64);
    if (lane == 0) sred[w] = v;
    __syncthreads();
    float t = (threadIdx.x < (int)(blockDim.x >> 6)) ? sred[threadIdx.x] : 0.f;
    if (w == 0) {
#pragma unroll
        for (int off = 4; off > 0; off >>= 1) t += __shfl_down(t, off, 64);
        if (lane == 0) sred[0] = t;
    }
    __syncthreads();
    return sred[0];
}

// ---------------- K0: W[K][N] f32 -> WT[NP][K] bf16 (zero-pad n>=N) ----------
__global__ __launch_bounds__(256) void transpose_to_bf16_kernel(
    const float* __restrict__ W, bf16* __restrict__ WT, int K, int N) {
    __shared__ float t[32][33];
    int n0 = blockIdx.x * 32, k0 = blockIdx.y * 32;
    int tx = threadIdx.x & 31, ty = threadIdx.x >> 5;   // 32 x 8
#pragma unroll
    for (int r = 0; r < 32; r += 8) {
        int k = k0 + ty + r, n = n0 + tx;
        t[ty + r][tx] = (n < N) ? W[(size_t)k * N + n] : 0.f;
    }
    __syncthreads();
#pragma unroll
    for (int r = 0; r < 32; r += 8) {
        int n = n0 + ty + r, k = k0 + tx;
        WT[(size_t)n * K + k] = __float2bfloat16(t[tx][ty + r]);
    }
}

// ---------------- K1: res = hid + residual; h = rmsnorm(res)*w (bf16) --------
__global__ __launch_bounds__(256) void add_rmsnorm_kernel(
    const float* __restrict__ hid, const float* __restrict__ resid,
    const float* __restrict__ w, float* __restrict__ res_out,
    bf16* __restrict__ h_out) {
    int r = blockIdx.x;
    int tid = threadIdx.x;
    size_t base = (size_t)r * DM;
    float4 hv = *(const float4*)&hid[base + tid * 4];
    float4 rv = *(const float4*)&resid[base + tid * 4];
    float4 s = {hv.x + rv.x, hv.y + rv.y, hv.z + rv.z, hv.w + rv.w};
    *(float4*)&res_out[base + tid * 4] = s;
    float ss = s.x * s.x + s.y * s.y + s.z * s.z + s.w * s.w;
    ss = block_reduce_sum(ss);
    float scale = rsqrtf(ss / (float)DM + EPS);
    float4 wv = *(const float4*)&w[tid * 4];
    __hip_bfloat162 p0, p1;
    p0.x = __float2bfloat16(s.x * scale * wv.x);
    p0.y = __float2bfloat16(s.y * scale * wv.y);
    p1.x = __float2bfloat16(s.z * scale * wv.z);
    p1.y = __float2bfloat16(s.w * scale * wv.w);
    bf16* hp = &h_out[base + tid * 4];
    *(__hip_bfloat162*)hp = p0;
    *(__hip_bfloat162*)(hp + 2) = p1;
}

// ---------------- MFMA GEMM: C[M,N] = A[M,K](bf16,lda) @ Bt[Npad,K]^T --------
// m97 pattern: 128x128 tile, BK=32, 4 waves 2x2, 16 MFMAs/wave/iter,
// global_load_lds width 16, 2-barrier K-loop. M%128==0, K%32==0; n guarded.
template <int WRITE_F32>
__global__ __launch_bounds__(256) void gemm_mfma_kernel(
    const bf16* __restrict__ A, int lda, const bf16* __restrict__ Bt,
    void* __restrict__ C, int ldc, int M, int N, int K,
    float* __restrict__ dtraw) {
    __shared__ __align__(16) bf16 As[128 * 32];
    __shared__ __align__(16) bf16 Bs[128 * 32];
    int tid = threadIdx.x;
    int lane = tid & 63, wave = tid >> 6;
    int wm = (wave >> 1) * 64, wn = (wave & 1) * 64;
    int m0 = blockIdx.y * 128, n0 = blockIdx.x * 128;
    int fr = lane & 15, kg = lane >> 4;        // fragment row / k-group

    // staging: 8 KB per tile = 512 chunks of 16B; thread t does chunks t, t+256
    int off0 = tid * 16, off1 = off0 + 4096;
    int row0 = off0 >> 6, colb0 = off0 & 63;
    int row1 = off1 >> 6, colb1 = off1 & 63;
    const bf16* ga0 = A + (size_t)(m0 + row0) * lda + (colb0 >> 1);
    const bf16* ga1 = A + (size_t)(m0 + row1) * lda + (colb1 >> 1);
    const bf16* gb0 = Bt + (size_t)(n0 + row0) * K + (colb0 >> 1);
    const bf16* gb1 = Bt + (size_t)(n0 + row1) * K + (colb1 >> 1);

    f32x4v acc[4][4] = {};
    for (int k0 = 0; k0 < K; k0 += 32) {
        __syncthreads();
        __builtin_amdgcn_global_load_lds(
            (const __attribute__((address_space(1))) void*)(ga0 + k0),
            (__attribute__((address_space(3))) void*)((char*)As + off0), 16, 0, 0);
        __builtin_amdgcn_global_load_lds(
            (const __attribute__((address_space(1))) void*)(ga1 + k0),
            (__attribute__((address_space(3))) void*)((char*)As + off1), 16, 0, 0);
        __builtin_amdgcn_global_load_lds(
            (const __attribute__((address_space(1))) void*)(gb0 + k0),
            (__attribute__((address_space(3))) void*)((char*)Bs + off0), 16, 0, 0);
        __builtin_amdgcn_global_load_lds(
            (const __attribute__((address_space(1))) void*)(gb1 + k0),
            (__attribute__((address_space(3))) void*)((char*)Bs + off1), 16, 0, 0);
        __syncthreads();
        bf16x8v af[4], bfv[4];
#pragma unroll
        for (int mt = 0; mt < 4; ++mt)
            af[mt] = *(const bf16x8v*)&As[(wm + mt * 16 + fr) * 32 + kg * 8];
#pragma unroll
        for (int nt = 0; nt < 4; ++nt)
            bfv[nt] = *(const bf16x8v*)&Bs[(wn + nt * 16 + fr) * 32 + kg * 8];
#pragma unroll
        for (int mt = 0; mt < 4; ++mt)
#pragma unroll
            for (int nt = 0; nt < 4; ++nt)
                acc[mt][nt] = __builtin_amdgcn_mfma_f32_16x16x32_bf16(
                    af[mt], bfv[nt], acc[mt][nt], 0, 0, 0);
    }
    // epilogue: C/D map col=lane&15, row=(lane>>4)*4+reg
    int col = lane & 15, rbase = (lane >> 4) * 4;
#pragma unroll
    for (int mt = 0; mt < 4; ++mt) {
#pragma unroll
        for (int nt = 0; nt < 4; ++nt) {
            int gn = n0 + wn + nt * 16 + col;
            if (gn >= N) continue;
#pragma unroll
            for (int rg = 0; rg < 4; ++rg) {
                int gm = m0 + wm + mt * 16 + rbase + rg;
                float v = acc[mt][nt][rg];
                if (WRITE_F32) {
                    ((float*)C)[(size_t)gm * ldc + gn] = v;
                } else {
                    ((bf16*)C)[(size_t)gm * ldc + gn] = __float2bfloat16(v);
                    if (dtraw && gn >= 4352)
                        dtraw[(size_t)gm * 32 + (gn - 4352)] = v;
                }
            }
        }
    }
}

// ---------------- K3: depthwise causal conv(4) + bias + SiLU ----------------
__global__ __launch_bounds__(256) void conv_silu_kernel(
    const bf16* __restrict__ zx, const float* __restrict__ conv_w,
    const float* __restrict__ conv_b, bf16* __restrict__ xBC) {
    int idx = blockIdx.x * 256 + threadIdx.x;
    int r = idx / XBC_C;
    int c = idx - r * XBC_C;
    int b = r >> 12, l = r & (LQ - 1);
    float acc = conv_b[c];
#pragma unroll
    for (int k = 0; k < 4; ++k) {
        int t = l - 3 + k;
        if (t >= 0)
            acc = fmaf(conv_w[k * XBC_C + c],
                       __bfloat162float(zx[(size_t)(b * LQ + t) * ZX_C + DI + c]), acc);
    }
    xBC[(size_t)r * XBC_C + c] = __float2bfloat16(acc / (1.f + __expf(-acc)));
}

// ---------------- K3b: dt = softplus(dt_raw + bias); chunk cumsum of dt*A ----
__global__ __launch_bounds__(256) void dt_scan_kernel(
    const float* __restrict__ dtraw, const float* __restrict__ dt_bias,
    const float* __restrict__ A_log, float* __restrict__ dt_bh,
    float* __restrict__ Acum_bh) {
    __shared__ float sA[256];
    int bid = blockIdx.x;                       // (b,h,c)
    int c = bid & 15, h = (bid >> 4) & 31, b = bid >> 9;
    int tid = threadIdx.x;
    int l = c * CH + tid;
    int r = b * LQ + l;
    float v = dtraw[(size_t)r * 32 + h] + dt_bias[h];
    float dt = (v > 20.f) ? v : log1pf(expf(v));
    float A = -expf(A_log[h]);
    sA[tid] = dt * A;
    __syncthreads();
    for (int off = 1; off < 256; off <<= 1) {
        float t = (tid >= off) ? sA[tid - off] : 0.f;
        __syncthreads();
        sA[tid] += t;
        __syncthreads();
    }
    size_t o = (size_t)(b * NH + h) * LQ + l;
    dt_bh[o] = dt;
    Acum_bh[o] = sA[tid];
}

// ---------------- K4a: states[p,n] = sum_l B[l,n]*dt[l]*decay[l]*x[l,p] ------
__global__ __launch_bounds__(256) void states_kernel(
    const bf16* __restrict__ xBC, const float* __restrict__ dt_bh,
    const float* __restrict__ Acum_bh, float* __restrict__ states) {
    __shared__ float Bt[64][129];
    __shared__ float Xt[64][65];
    __shared__ float sc[64];
    int bid = blockIdx.x;                       // (b,h,c)
    int c = bid & 15, h = (bid >> 4) & 31, b = bid >> 9;
    int bh = b * NH + h;
    int tid = threadIdx.x;
    int tx = tid & 15, ty = tid >> 4;
    float acc[4][8] = {};
    float Alast = Acum_bh[(size_t)bh * LQ + c * CH + (CH - 1)];
    for (int lt = 0; lt < 4; ++lt) {
        int s0 = lt * 64;
        int rs0 = b * LQ + c * CH + s0;
        if (tid < 64) {
            float ac = Acum_bh[(size_t)bh * LQ + c * CH + s0 + tid];
            float dtv = dt_bh[(size_t)bh * LQ + c * CH + s0 + tid];
            sc[tid] = dtv * __expf(Alast - ac);
        }
        {
            int n = tid & 127, sr = tid >> 7;
#pragma unroll
            for (int r = 0; r < 32; ++r)
                Bt[sr + r * 2][n] =
                    __bfloat162float(xBC[(size_t)(rs0 + sr + r * 2) * XBC_C + DI + n]);
        }
        {
            int p = tid & 63, sr = tid >> 6;
#pragma unroll
            for (int r = 0; r < 16; ++r)
                Xt[sr + r * 4][p] =
                    __bfloat162float(xBC[(size_t)(rs0 + sr + r * 4) * XBC_C + h * HD + p]);
        }
        __syncthreads();
#pragma unroll 4
        for (int k = 0; k < 64; ++k) {
            float s = sc[k];
            float a[4], bb[8];
#pragma unroll
            for (int q = 0; q < 4; ++q) a[q] = Xt[k][ty * 4 + q] * s;
#pragma unroll
            for (int q = 0; q < 8; ++q) bb[q] = Bt[k][tx * 8 + q];
#pragma unroll
            for (int i = 0; i < 4; ++i)
#pragma unroll
                for (int j = 0; j < 8; ++j)
                    acc[i][j] = fmaf(a[i], bb[j], acc[i][j]);
        }
        __syncthreads();
    }
    size_t base = (size_t)(bh * NC + c) * HD * DS;
#pragma unroll
    for (int i = 0; i < 4; ++i) {
        int p = ty * 4 + i;
#pragma unroll
        for (int j = 0; j < 8; ++j) {
            int n = tx * 8 + j;
            states[base + (size_t)p * DS + n] = acc[i][j];
        }
    }
}

// ---------------- K5: inter-chunk scan, in place ------------------------------
__global__ __launch_bounds__(256) void chunk_scan_kernel(
    float* __restrict__ states, const float* __restrict__ Acum_bh) {
    int bh = blockIdx.x;
    int tid = threadIdx.x;
    float carry[32];
#pragma unroll
    for (int j = 0; j < 32; ++j) carry[j] = 0.f;
    for (int c = 0; c < NC; ++c) {
        float dec = __expf(Acum_bh[(size_t)bh * LQ + c * CH + (CH - 1)]);
        size_t base = (size_t)(bh * NC + c) * (HD * DS);
#pragma unroll
        for (int j = 0; j < 32; ++j) {
            size_t idx = base + tid + j * 256;
            float tmp = states[idx];
            states[idx] = carry[j];
            carry[j] = carry[j] * dec + tmp;
        }
    }
}

// ---------------- K4b: Y = diag + off + D*x; bf16 out, strided ZX_C ----------
__global__ __launch_bounds__(256) void y_kernel(
    const bf16* __restrict__ xBC, const float* __restrict__ dt_bh,
    const float* __restrict__ Acum_bh, const float* __restrict__ prev,
    const float* __restrict__ Dvec, bf16* __restrict__ yout /* zx+2048, lda ZX_C */) {
    __shared__ float Cl[64][129];
    __shared__ float Wbuf[64 * 129];  // W tile; St[64][65] aliases the front
    __shared__ bf16 Xs[64][66];
    __shared__ float AclS[64];
    __shared__ float AsS[64];
#define Wm(i, j)  Wbuf[(i) * 129 + (j)]
#define Stm(i, j) Wbuf[(i) * 65 + (j)]
    int bid = blockIdx.x;                       // (b,h,c,lt)
    int lt = bid & 3, c = (bid >> 2) & 15, h = (bid >> 6) & 31, b = bid >> 11;
    int tid = threadIdx.x;
    int tx = tid & 15, ty = tid >> 4;
    int bh = b * NH + h;
    int l0 = lt * 64;
    int r0 = b * LQ + c * CH + l0;
    {
        int n = tid & 127, lr = tid >> 7;
#pragma unroll
        for (int r = 0; r < 32; ++r)
            Cl[lr + r * 2][n] =
                __bfloat162float(xBC[(size_t)(r0 + lr + r * 2) * XBC_C + DI + DS + n]);
    }
    if (tid < 64) AclS[tid] = Acum_bh[(size_t)bh * LQ + c * CH + l0 + tid];
    {
        int n = tid & 127, pr = tid >> 7;
        size_t base = (size_t)(bh * NC + c) * HD * DS;
#pragma unroll
        for (int r = 0; r < 32; ++r)
            Wm(pr + r * 2, n) = prev[base + (size_t)(pr + r * 2) * DS + n];
    }
    __syncthreads();
    float accoff[4][4] = {};
#pragma unroll 4
    for (int k = 0; k < 128; ++k) {
        float a[4], bb[4];
#pragma unroll
        for (int q = 0; q < 4; ++q) a[q] = Cl[ty * 4 + q][k];
#pragma unroll
        for (int q = 0; q < 4; ++q) bb[q] = Wm(tx * 4 + q, k);
#pragma unroll
        for (int i = 0; i < 4; ++i)
#pragma unroll
            for (int j = 0; j < 4; ++j)
                accoff[i][j] = fmaf(a[i], bb[j], accoff[i][j]);
    }
    __syncthreads();
    float acc[4][4] = {};
    for (int st = 0; st <= lt; ++st) {
        int s0 = st * 64;
        int rs0 = b * LQ + c * CH + s0;
        {
            int n = tid & 127, sr = tid >> 7;
#pragma unroll
            for (int r = 0; r < 32; ++r)
                Wm(sr + r * 2, n) =
                    __bfloat162float(xBC[(size_t)(rs0 + sr + r * 2) * XBC_C + DI + n]);
        }
        {
            int p = tid & 63, sr = tid >> 6;
#pragma unroll
            for (int r = 0; r < 16; ++r) {
                int s = sr + r * 4;
                float dtv = dt_bh[(size_t)bh * LQ + c * CH + s0 + s];
                float xv = __bfloat162float(xBC[(size_t)(rs0 + s) * XBC_C + h * HD + p]);
                Xs[s][p] = __float2bfloat16(xv * dtv);
            }
        }
        if (tid < 64) AsS[tid] = Acum_bh[(size_t)bh * LQ + c * CH + s0 + tid];
        __syncthreads();
        float sreg[4][4] = {};
#pragma unroll 4
        for (int k = 0; k < 128; ++k) {
            float a[4], bb[4];
#pragma unroll
            for (int q = 0; q < 4; ++q) a[q] = Cl[ty * 4 + q][k];
#pragma unroll
            for (int q = 0; q < 4; ++q) bb[q] = Wm(tx * 4 + q, k);
#pragma unroll
            for (int i = 0; i < 4; ++i)
#pragma unroll
                for (int j = 0; j < 4; ++j)
                    sreg[i][j] = fmaf(a[i], bb[j], sreg[i][j]);
        }
        __syncthreads();   // all W reads done before St (aliased) is written
#pragma unroll
        for (int i = 0; i < 4; ++i) {
            int lg = l0 + ty * 4 + i;
            float al = AclS[ty * 4 + i];
#pragma unroll
            for (int j = 0; j < 4; ++j) {
                int sg = s0 + tx * 4 + j;
                float v = (sg <= lg) ? sreg[i][j] * __expf(al - AsS[tx * 4 + j]) : 0.f;
                Stm(ty * 4 + i, tx * 4 + j) = v;
            }
        }
        __syncthreads();
#pragma unroll 4
        for (int k = 0; k < 64; ++k) {
            float a[4], bb[4];
#pragma unroll
            for (int q = 0; q < 4; ++q) a[q] = Stm(ty * 4 + q, k);
#pragma unroll
            for (int q = 0; q < 4; ++q) bb[q] = __bfloat162float(Xs[k][tx * 4 + q]);
#pragma unroll
            for (int i = 0; i < 4; ++i)
#pragma unroll
                for (int j = 0; j < 4; ++j)
                    acc[i][j] = fmaf(a[i], bb[j], acc[i][j]);
        }
        __syncthreads();
    }
    float Dh = Dvec[h];
#pragma unroll
    for (int i = 0; i < 4; ++i) {
        int l = ty * 4 + i;
        float e = __expf(AclS[l]);
        int gr = r0 + l;
        const bf16* xp = &xBC[(size_t)gr * XBC_C + h * HD + tx * 4];
        float ov[4];
#pragma unroll
        for (int j = 0; j < 4; ++j)
            ov[j] = acc[i][j] + e * accoff[i][j] + Dh * __bfloat162float(xp[j]);
        bf16* yp = yout + (size_t)gr * ZX_C + h * HD + tx * 4;
        __hip_bfloat162 p0, p1;
        p0.x = __float2bfloat16(ov[0]); p0.y = __float2bfloat16(ov[1]);
        p1.x = __float2bfloat16(ov[2]); p1.y = __float2bfloat16(ov[3]);
        *(__hip_bfloat162*)yp = p0;
        *(__hip_bfloat162*)(yp + 2) = p1;
    }
#undef Wm
#undef Stm
}

// ---------------- K6: y = rmsnorm(y * silu(z)) * gw, in place (strided) ------
__global__ __launch_bounds__(256) void gate_norm_kernel(
    const bf16* __restrict__ zx, const float* __restrict__ gw,
    bf16* __restrict__ y /* zx+2048, lda ZX_C */) {
    int r = blockIdx.x;
    int tid = threadIdx.x;
    float v[8];
    float ss = 0.f;
#pragma unroll
    for (int q = 0; q < 8; ++q) {
        int i = tid + q * 256;
        float z = __bfloat162float(zx[(size_t)r * ZX_C + i]);
        float val = __bfloat162float(y[(size_t)r * ZX_C + i]) * (z / (1.f + __expf(-z)));
        v[q] = val;
        ss += val * val;
    }
    ss = block_reduce_sum(ss);
    float scale = rsqrtf(ss / (float)DI + EPS);
#pragma unroll
    for (int q = 0; q < 8; ++q) {
        int i = tid + q * 256;
        y[(size_t)r * ZX_C + i] = __float2bfloat16(v[q] * scale * gw[i]);
    }
}

// ---------------- launch ----------------
extern "C" void kernel_launch(void* const* d_in, const int* in_sizes, int n_in,
                              void* d_out, int out_size, void* d_ws, size_t ws_size,
                              hipStream_t stream) {
    const float* hid      = (const float*)d_in[0];
    const float* resid    = (const float*)d_in[1];
    const float* norm_w   = (const float*)d_in[2];
    const float* in_proj  = (const float*)d_in[3];
    const float* conv_w   = (const float*)d_in[4];
    const float* conv_b   = (const float*)d_in[5];
    const float* dt_bias  = (const float*)d_in[6];
    const float* A_log    = (const float*)d_in[7];
    const float* Dvec     = (const float*)d_in[8];
    const float* gate_w   = (const float*)d_in[9];
    const float* out_proj = (const float*)d_in[10];

    float* out_p   = (float*)d_out;                  // [8192,1024] f32
    float* res_out = out_p + (size_t)RTOT * DM;      // [8192,1024] f32
    // out region timeline: h_bf16 (K1 -> GEMM1) ; states (K4a -> K4b) ; out (GEMM2)
    bf16*  h_bf16  = (bf16*)out_p;                   // 16.8 MB
    float* states  = out_p;                          // 33.55 MB (exact fit)

    // workspace ~113 MB
    char* wsb = (char*)d_ws;
    bf16*  zx      = (bf16*)wsb;  wsb += (size_t)RTOT * ZX_C * sizeof(bf16);   // 71.8 MB
    bf16*  xBC     = (bf16*)wsb;  wsb += (size_t)RTOT * XBC_C * sizeof(bf16);  // 37.7 MB
    float* dtraw   = (float*)wsb; wsb += (size_t)RTOT * 32 * sizeof(float);
    float* dt_bh   = (float*)wsb; wsb += (size_t)BATCH * NH * LQ * sizeof(float);
    float* Acum_bh = (float*)wsb; wsb += (size_t)BATCH * NH * LQ * sizeof(float);
    // Bt1/Bt2 alias the xBC region (dead at their respective times)
    bf16* Bt1 = xBC;      // [4480][1024] = 9.2 MB, dead after GEMM1 (conv overwrites)
    bf16* Bt2 = xBC;      // [1024][2048] = 4.2 MB, written after y_kernel

    // 1) weight transpose for GEMM1 (into Bt1 region)
    transpose_to_bf16_kernel<<<dim3(NP1 / 32, DM / 32), 256, 0, stream>>>(
        in_proj, Bt1, DM, ZX_C);
    // 2) add + rmsnorm -> res_out (f32), h (bf16)
    add_rmsnorm_kernel<<<RTOT, 256, 0, stream>>>(hid, resid, norm_w, res_out, h_bf16);
    // 3) GEMM1 (MFMA): zx[8192,4384] bf16 (+ dtraw f32 side channel)
    gemm_mfma_kernel<0><<<dim3(NP1 / 128, RTOT / 128), 256, 0, stream>>>(
        h_bf16, DM, Bt1, zx, ZX_C, RTOT, ZX_C, DM, dtraw);
    // 4) conv + SiLU (overwrites Bt1 region -- GEMM1 already consumed it)
    conv_silu_kernel<<<(RTOT * XBC_C) / 256, 256, 0, stream>>>(
        zx, conv_w, conv_b, xBC);
    // 5) dt softplus + chunk-local cumsum
    dt_scan_kernel<<<BATCH * NH * NC, 256, 0, stream>>>(
        dtraw, dt_bias, A_log, dt_bh, Acum_bh);
    // 6) per-chunk states (overwrites h region -- GEMM1 done)
    states_kernel<<<BATCH * NH * NC, 256, 0, stream>>>(
        xBC, dt_bh, Acum_bh, states);
    // 7) inter-chunk recurrence
    chunk_scan_kernel<<<BATCH * NH, 256, 0, stream>>>(states, Acum_bh);
    // 8) Y (diag + off + D-term) -> zx cols [2048,4096)
    y_kernel<<<BATCH * NH * NC * 4, 256, 0, stream>>>(
        xBC, dt_bh, Acum_bh, states, Dvec, zx + DI);
    // 9) weight transpose for GEMM2 (xBC dead now)
    transpose_to_bf16_kernel<<<dim3(DM / 32, DI / 32), 256, 0, stream>>>(
        out_proj, Bt2, DI, DM);
    // 10) gated RMSNorm in place
    gate_norm_kernel<<<RTOT, 256, 0, stream>>>(zx, gate_w, zx + DI);
    // 11) GEMM2 (MFMA): out[8192,1024] f32
    gemm_mfma_kernel<1><<<dim3(DM / 128, RTOT / 128), 256, 0, stream>>>(
        zx + DI, ZX_C, Bt2, out_p, DM, RTOT, DM, DI, nullptr);
}

// Round 5
// 691.925 us; speedup vs baseline: 3.5127x; 1.6327x over previous
//
#include <hip/hip_runtime.h>
#include <hip/hip_bf16.h>
#include <math.h>

// ---------------- geometry ----------------
#define BATCH   2
#define LQ      4096            // seqlen
#define RTOT    8192            // BATCH*LQ rows
#define DM      1024            // d_model
#define DI      2048            // d_inner
#define NH      32              // heads
#define HD      64              // head dim p
#define DS      128             // d_state n
#define CH      256             // chunk
#define NC      16              // chunks per seq
#define XBC_C   2304            // conv channels
#define ZX_C    4384            // in_proj output cols
#define NP1     4480            // padded N for gemm1 B^T (35*128)
#define EPS     1e-5f

typedef __hip_bfloat16 bf16;
typedef __bf16 bf16x8v __attribute__((ext_vector_type(8)));
typedef float f32x4v __attribute__((ext_vector_type(4)));

// ---------------- block reduce ----------------
__device__ __forceinline__ float block_reduce_sum(float v) {
    __shared__ float sred[8];
    int lane = threadIdx.x & 63, w = threadIdx.x >> 6;
#pragma unroll
    for (int off = 32; off > 0; off >>= 1) v += __shfl_down(v, off, 64);
    if (lane == 0) sred[w] = v;
    __syncthreads();
    float t = (threadIdx.x < (int)(blockDim.x >> 6)) ? sred[threadIdx.x] : 0.f;
    if (w == 0) {
#pragma unroll
        for (int off = 4; off > 0; off >>= 1) t += __shfl_down(t, off, 64);
        if (lane == 0) sred[0] = t;
    }
    __syncthreads();
    return sred[0];
}

// ---------------- K0: W[K][N] f32 -> WT[NP][K] bf16 (zero-pad n>=N) ----------
__global__ __launch_bounds__(256) void transpose_to_bf16_kernel(
    const float* __restrict__ W, bf16* __restrict__ WT, int K, int N) {
    __shared__ float t[32][33];
    int n0 = blockIdx.x * 32, k0 = blockIdx.y * 32;
    int tx = threadIdx.x & 31, ty = threadIdx.x >> 5;   // 32 x 8
#pragma unroll
    for (int r = 0; r < 32; r += 8) {
        int k = k0 + ty + r, n = n0 + tx;
        t[ty + r][tx] = (n < N) ? W[(size_t)k * N + n] : 0.f;
    }
    __syncthreads();
#pragma unroll
    for (int r = 0; r < 32; r += 8) {
        int n = n0 + ty + r, k = k0 + tx;
        WT[(size_t)n * K + k] = __float2bfloat16(t[tx][ty + r]);
    }
}

// ---------------- K1: res = hid + residual; h = rmsnorm(res)*w (bf16) --------
__global__ __launch_bounds__(256) void add_rmsnorm_kernel(
    const float* __restrict__ hid, const float* __restrict__ resid,
    const float* __restrict__ w, float* __restrict__ res_out,
    bf16* __restrict__ h_out) {
    int r = blockIdx.x;
    int tid = threadIdx.x;
    size_t base = (size_t)r * DM;
    float4 hv = *(const float4*)&hid[base + tid * 4];
    float4 rv = *(const float4*)&resid[base + tid * 4];
    float4 s = {hv.x + rv.x, hv.y + rv.y, hv.z + rv.z, hv.w + rv.w};
    *(float4*)&res_out[base + tid * 4] = s;
    float ss = s.x * s.x + s.y * s.y + s.z * s.z + s.w * s.w;
    ss = block_reduce_sum(ss);
    float scale = rsqrtf(ss / (float)DM + EPS);
    float4 wv = *(const float4*)&w[tid * 4];
    __hip_bfloat162 p0, p1;
    p0.x = __float2bfloat16(s.x * scale * wv.x);
    p0.y = __float2bfloat16(s.y * scale * wv.y);
    p1.x = __float2bfloat16(s.z * scale * wv.z);
    p1.y = __float2bfloat16(s.w * scale * wv.w);
    bf16* hp = &h_out[base + tid * 4];
    *(__hip_bfloat162*)hp = p0;
    *(__hip_bfloat162*)(hp + 2) = p1;
}

// ---------------- MFMA GEMM: C[M,N] = A[M,K](bf16,lda) @ Bt[Npad,K]^T --------
template <int WRITE_F32>
__global__ __launch_bounds__(256) void gemm_mfma_kernel(
    const bf16* __restrict__ A, int lda, const bf16* __restrict__ Bt,
    void* __restrict__ C, int ldc, int M, int N, int K,
    float* __restrict__ dtraw) {
    __shared__ __align__(16) bf16 As[128 * 32];
    __shared__ __align__(16) bf16 Bs[128 * 32];
    int tid = threadIdx.x;
    int lane = tid & 63, wave = tid >> 6;
    int wm = (wave >> 1) * 64, wn = (wave & 1) * 64;
    int m0 = blockIdx.y * 128, n0 = blockIdx.x * 128;
    int fr = lane & 15, kg = lane >> 4;

    int off0 = tid * 16, off1 = off0 + 4096;
    int row0 = off0 >> 6, colb0 = off0 & 63;
    int row1 = off1 >> 6, colb1 = off1 & 63;
    const bf16* ga0 = A + (size_t)(m0 + row0) * lda + (colb0 >> 1);
    const bf16* ga1 = A + (size_t)(m0 + row1) * lda + (colb1 >> 1);
    const bf16* gb0 = Bt + (size_t)(n0 + row0) * K + (colb0 >> 1);
    const bf16* gb1 = Bt + (size_t)(n0 + row1) * K + (colb1 >> 1);

    f32x4v acc[4][4] = {};
    for (int k0 = 0; k0 < K; k0 += 32) {
        __syncthreads();
        __builtin_amdgcn_global_load_lds(
            (const __attribute__((address_space(1))) void*)(ga0 + k0),
            (__attribute__((address_space(3))) void*)((char*)As + off0), 16, 0, 0);
        __builtin_amdgcn_global_load_lds(
            (const __attribute__((address_space(1))) void*)(ga1 + k0),
            (__attribute__((address_space(3))) void*)((char*)As + off1), 16, 0, 0);
        __builtin_amdgcn_global_load_lds(
            (const __attribute__((address_space(1))) void*)(gb0 + k0),
            (__attribute__((address_space(3))) void*)((char*)Bs + off0), 16, 0, 0);
        __builtin_amdgcn_global_load_lds(
            (const __attribute__((address_space(1))) void*)(gb1 + k0),
            (__attribute__((address_space(3))) void*)((char*)Bs + off1), 16, 0, 0);
        __syncthreads();
        bf16x8v af[4], bfv[4];
#pragma unroll
        for (int mt = 0; mt < 4; ++mt)
            af[mt] = *(const bf16x8v*)&As[(wm + mt * 16 + fr) * 32 + kg * 8];
#pragma unroll
        for (int nt = 0; nt < 4; ++nt)
            bfv[nt] = *(const bf16x8v*)&Bs[(wn + nt * 16 + fr) * 32 + kg * 8];
#pragma unroll
        for (int mt = 0; mt < 4; ++mt)
#pragma unroll
            for (int nt = 0; nt < 4; ++nt)
                acc[mt][nt] = __builtin_amdgcn_mfma_f32_16x16x32_bf16(
                    af[mt], bfv[nt], acc[mt][nt], 0, 0, 0);
    }
    int col = lane & 15, rbase = (lane >> 4) * 4;
#pragma unroll
    for (int mt = 0; mt < 4; ++mt) {
#pragma unroll
        for (int nt = 0; nt < 4; ++nt) {
            int gn = n0 + wn + nt * 16 + col;
            if (gn >= N) continue;
#pragma unroll
            for (int rg = 0; rg < 4; ++rg) {
                int gm = m0 + wm + mt * 16 + rbase + rg;
                float v = acc[mt][nt][rg];
                if (WRITE_F32) {
                    ((float*)C)[(size_t)gm * ldc + gn] = v;
                } else {
                    ((bf16*)C)[(size_t)gm * ldc + gn] = __float2bfloat16(v);
                    if (dtraw && gn >= 4352)
                        dtraw[(size_t)gm * 32 + (gn - 4352)] = v;
                }
            }
        }
    }
}

// ---------------- K3: depthwise causal conv(4) + bias + SiLU ----------------
__global__ __launch_bounds__(256) void conv_silu_kernel(
    const bf16* __restrict__ zx, const float* __restrict__ conv_w,
    const float* __restrict__ conv_b, bf16* __restrict__ xBC) {
    int idx = blockIdx.x * 256 + threadIdx.x;
    int r = idx / XBC_C;
    int c = idx - r * XBC_C;
    int b = r >> 12, l = r & (LQ - 1);
    float acc = conv_b[c];
#pragma unroll
    for (int k = 0; k < 4; ++k) {
        int t = l - 3 + k;
        if (t >= 0)
            acc = fmaf(conv_w[k * XBC_C + c],
                       __bfloat162float(zx[(size_t)(b * LQ + t) * ZX_C + DI + c]), acc);
    }
    xBC[(size_t)r * XBC_C + c] = __float2bfloat16(acc / (1.f + __expf(-acc)));
}

// ---------------- K3b: dt = softplus(dt_raw + bias); chunk cumsum of dt*A ----
__global__ __launch_bounds__(256) void dt_scan_kernel(
    const float* __restrict__ dtraw, const float* __restrict__ dt_bias,
    const float* __restrict__ A_log, float* __restrict__ dt_bh,
    float* __restrict__ Acum_bh) {
    __shared__ float sA[256];
    int bid = blockIdx.x;                       // (b,h,c)
    int c = bid & 15, h = (bid >> 4) & 31, b = bid >> 9;
    int tid = threadIdx.x;
    int l = c * CH + tid;
    int r = b * LQ + l;
    float v = dtraw[(size_t)r * 32 + h] + dt_bias[h];
    float dt = (v > 20.f) ? v : log1pf(expf(v));
    float A = -expf(A_log[h]);
    sA[tid] = dt * A;
    __syncthreads();
    for (int off = 1; off < 256; off <<= 1) {
        float t = (tid >= off) ? sA[tid - off] : 0.f;
        __syncthreads();
        sA[tid] += t;
        __syncthreads();
    }
    size_t o = (size_t)(b * NH + h) * LQ + l;
    dt_bh[o] = dt;
    Acum_bh[o] = sA[tid];
}

// ---------------- K4a: states[p,n] = sum_l B[l,n]*dt[l]*decay[l]*x[l,p] ------
__global__ __launch_bounds__(256) void states_kernel(
    const bf16* __restrict__ xBC, const float* __restrict__ dt_bh,
    const float* __restrict__ Acum_bh, float* __restrict__ states) {
    __shared__ float Bt[64][129];
    __shared__ float Xt[64][65];
    __shared__ float sc[64];
    int bid = blockIdx.x;                       // (b,h,c)
    int c = bid & 15, h = (bid >> 4) & 31, b = bid >> 9;
    int bh = b * NH + h;
    int tid = threadIdx.x;
    int tx = tid & 15, ty = tid >> 4;
    float acc[4][8] = {};
    float Alast = Acum_bh[(size_t)bh * LQ + c * CH + (CH - 1)];
    for (int lt = 0; lt < 4; ++lt) {
        int s0 = lt * 64;
        int rs0 = b * LQ + c * CH + s0;
        if (tid < 64) {
            float ac = Acum_bh[(size_t)bh * LQ + c * CH + s0 + tid];
            float dtv = dt_bh[(size_t)bh * LQ + c * CH + s0 + tid];
            sc[tid] = dtv * __expf(Alast - ac);
        }
        {
            int n = tid & 127, sr = tid >> 7;
#pragma unroll
            for (int r = 0; r < 32; ++r)
                Bt[sr + r * 2][n] =
                    __bfloat162float(xBC[(size_t)(rs0 + sr + r * 2) * XBC_C + DI + n]);
        }
        {
            int p = tid & 63, sr = tid >> 6;
#pragma unroll
            for (int r = 0; r < 16; ++r)
                Xt[sr + r * 4][p] =
                    __bfloat162float(xBC[(size_t)(rs0 + sr + r * 4) * XBC_C + h * HD + p]);
        }
        __syncthreads();
#pragma unroll 4
        for (int k = 0; k < 64; ++k) {
            float s = sc[k];
            float a[4], bb[8];
#pragma unroll
            for (int q = 0; q < 4; ++q) a[q] = Xt[k][ty * 4 + q] * s;
#pragma unroll
            for (int q = 0; q < 8; ++q) bb[q] = Bt[k][tx * 8 + q];
#pragma unroll
            for (int i = 0; i < 4; ++i)
#pragma unroll
                for (int j = 0; j < 8; ++j)
                    acc[i][j] = fmaf(a[i], bb[j], acc[i][j]);
        }
        __syncthreads();
    }
    size_t base = (size_t)(bh * NC + c) * HD * DS;
#pragma unroll
    for (int i = 0; i < 4; ++i) {
        int p = ty * 4 + i;
#pragma unroll
        for (int j = 0; j < 8; ++j) {
            int n = tx * 8 + j;
            states[base + (size_t)p * DS + n] = acc[i][j];
        }
    }
}

// ---------------- K5: inter-chunk scan, in place ------------------------------
__global__ __launch_bounds__(256) void chunk_scan_kernel(
    float* __restrict__ states, const float* __restrict__ Acum_bh) {
    int bh = blockIdx.x;
    int tid = threadIdx.x;
    float carry[32];
#pragma unroll
    for (int j = 0; j < 32; ++j) carry[j] = 0.f;
    for (int c = 0; c < NC; ++c) {
        float dec = __expf(Acum_bh[(size_t)bh * LQ + c * CH + (CH - 1)]);
        size_t base = (size_t)(bh * NC + c) * (HD * DS);
#pragma unroll
        for (int j = 0; j < 32; ++j) {
            size_t idx = base + tid + j * 256;
            float tmp = states[idx];
            states[idx] = carry[j];
            carry[j] = carry[j] * dec + tmp;
        }
    }
}

// ---------------- K4b (MFMA): Y = (C·B^T ∘ L)·xdt + exp(Acum)·(C·prev^T) -----
// One block per (b,h,c); wave w owns l-strip [w*64, w*64+64).
__global__ __launch_bounds__(256) void y_mfma_kernel(
    const bf16* __restrict__ xBC, const float* __restrict__ dt_bh,
    const float* __restrict__ Acum_bh, const float* __restrict__ prev,
    bf16* __restrict__ yout /* zx+2048, stride ZX_C */) {
    __shared__ __align__(16) bf16 xdtT[64][264];   // [p][s], stride 264
    __shared__ __align__(16) bf16 P[4][64][68];    // per-wave, stride 68
    __shared__ float As_sh[256];
    int bid = blockIdx.x;
    int c = bid & 15, h = (bid >> 4) & 31, b = bid >> 9;
    int bh = b * NH + h;
    int rch = b * LQ + c * CH;                     // chunk start row
    int tid = threadIdx.x;
    int wave = tid >> 6, lane = tid & 63;
    int fr = lane & 15, kg = lane >> 4;

    As_sh[tid] = Acum_bh[(size_t)bh * LQ + c * CH + tid];
    {   // xdtT[p][s] = x[s][p] * dt[s]
        int p2 = (tid & 31) * 2;
        int srow = tid >> 5;                       // 0..7
#pragma unroll 4
        for (int pass = 0; pass < 32; ++pass) {
            int s = pass * 8 + srow;
            float dtv = dt_bh[(size_t)bh * LQ + c * CH + s];
            __hip_bfloat162 xv =
                *(const __hip_bfloat162*)&xBC[(size_t)(rch + s) * XBC_C + h * HD + p2];
            xdtT[p2][s]     = __float2bfloat16(__bfloat162float(xv.x) * dtv);
            xdtT[p2 + 1][s] = __float2bfloat16(__bfloat162float(xv.y) * dtv);
        }
    }
    __syncthreads();

    // cache C A-fragments for this wave's strip: [mt][ks]
    bf16x8v CA[4][4];
    {
        size_t rb = (size_t)(rch + wave * 64 + fr) * XBC_C + DI + DS + kg * 8;
#pragma unroll
        for (int mt = 0; mt < 4; ++mt)
#pragma unroll
            for (int ks = 0; ks < 4; ++ks)
                CA[mt][ks] = *(const bf16x8v*)&xBC[rb + (size_t)mt * 16 * XBC_C + ks * 32];
    }

    f32x4v accY[4][4] = {};    // [mt][pt], D-layout

    // off-diagonal: C · prev^T
    {
        size_t pbase = (size_t)(bh * NC + c) * HD * DS;
#pragma unroll
        for (int ks = 0; ks < 4; ++ks) {
            bf16x8v PB[4];
#pragma unroll
            for (int pt = 0; pt < 4; ++pt) {
                const float* pp = &prev[pbase + (size_t)(pt * 16 + fr) * DS + ks * 32 + kg * 8];
                float4 a4 = *(const float4*)pp;
                float4 b4 = *(const float4*)(pp + 4);
                bf16x8v t;
                t[0] = (__bf16)a4.x; t[1] = (__bf16)a4.y; t[2] = (__bf16)a4.z; t[3] = (__bf16)a4.w;
                t[4] = (__bf16)b4.x; t[5] = (__bf16)b4.y; t[6] = (__bf16)b4.z; t[7] = (__bf16)b4.w;
                PB[pt] = t;
            }
#pragma unroll
            for (int mt = 0; mt < 4; ++mt)
#pragma unroll
                for (int pt = 0; pt < 4; ++pt)
                    accY[mt][pt] = __builtin_amdgcn_mfma_f32_16x16x32_bf16(
                        CA[mt][ks], PB[pt], accY[mt][pt], 0, 0, 0);
        }
    }
    int l0 = wave * 64;
    float eAl[4][4];           // exp(Acum[l]) per [mt][rg]
#pragma unroll
    for (int mt = 0; mt < 4; ++mt)
#pragma unroll
        for (int rg = 0; rg < 4; ++rg)
            eAl[mt][rg] = __expf(As_sh[l0 + mt * 16 + kg * 4 + rg]);
#pragma unroll
    for (int mt = 0; mt < 4; ++mt)
#pragma unroll
        for (int pt = 0; pt < 4; ++pt)
#pragma unroll
            for (int rg = 0; rg < 4; ++rg)
                accY[mt][pt][rg] *= eAl[mt][rg];

    // triangular diag part: st = 0..wave (no block barriers inside)
    for (int st = 0; st <= wave; ++st) {
        int s0 = st * 64;
#pragma unroll
        for (int half = 0; half < 2; ++half) {
            f32x4v Sacc[4][2] = {};
#pragma unroll
            for (int ks = 0; ks < 4; ++ks) {
                bf16x8v SB[2];
#pragma unroll
                for (int nh2 = 0; nh2 < 2; ++nh2) {
                    int nt = half * 2 + nh2;
                    SB[nh2] = *(const bf16x8v*)
                        &xBC[(size_t)(rch + s0 + nt * 16 + fr) * XBC_C + DI + ks * 32 + kg * 8];
                }
#pragma unroll
                for (int mt = 0; mt < 4; ++mt)
#pragma unroll
                    for (int nh2 = 0; nh2 < 2; ++nh2)
                        Sacc[mt][nh2] = __builtin_amdgcn_mfma_f32_16x16x32_bf16(
                            CA[mt][ks], SB[nh2], Sacc[mt][nh2], 0, 0, 0);
            }
            // mask + decay, write P (bf16, A-layout source)
#pragma unroll
            for (int mt = 0; mt < 4; ++mt) {
#pragma unroll
                for (int nh2 = 0; nh2 < 2; ++nh2) {
                    int nt = half * 2 + nh2;
                    int s_loc = s0 + nt * 16 + fr;
#pragma unroll
                    for (int rg = 0; rg < 4; ++rg) {
                        int l_loc = mt * 16 + kg * 4 + rg;
                        int l_idx = l0 + l_loc;
                        float v = 0.f;
                        if (s_loc <= l_idx)
                            v = Sacc[mt][nh2][rg] * __expf(As_sh[l_idx] - As_sh[s_loc]);
                        P[wave][l_loc][nt * 16 + fr] = __float2bfloat16(v);
                    }
                }
            }
        }
        __asm__ volatile("s_waitcnt lgkmcnt(0)" ::: "memory");
        // Y += P · xdt   (A from P-LDS, B from xdtT-LDS)
#pragma unroll
        for (int ks2 = 0; ks2 < 2; ++ks2) {
            bf16x8v PA[4], XB[4];
#pragma unroll
            for (int mt = 0; mt < 4; ++mt)
                PA[mt] = *(const bf16x8v*)&P[wave][mt * 16 + fr][ks2 * 32 + kg * 8];
#pragma unroll
            for (int pt = 0; pt < 4; ++pt)
                XB[pt] = *(const bf16x8v*)&xdtT[pt * 16 + fr][s0 + ks2 * 32 + kg * 8];
#pragma unroll
            for (int mt = 0; mt < 4; ++mt)
#pragma unroll
                for (int pt = 0; pt < 4; ++pt)
                    accY[mt][pt] = __builtin_amdgcn_mfma_f32_16x16x32_bf16(
                        PA[mt], XB[pt], accY[mt][pt], 0, 0, 0);
        }
    }

    // epilogue: stage through P for coalesced stores
#pragma unroll
    for (int mt = 0; mt < 4; ++mt)
#pragma unroll
        for (int pt = 0; pt < 4; ++pt)
#pragma unroll
            for (int rg = 0; rg < 4; ++rg)
                P[wave][mt * 16 + kg * 4 + rg][pt * 16 + fr] =
                    __float2bfloat16(accY[mt][pt][rg]);
    __asm__ volatile("s_waitcnt lgkmcnt(0)" ::: "memory");
    {
        bf16* yp = yout + (size_t)(rch + l0 + lane) * ZX_C + h * HD;
#pragma unroll
        for (int q = 0; q < 8; ++q) {
            bf16x8v v = *(const bf16x8v*)&P[wave][lane][q * 8];
            *(bf16x8v*)(yp + q * 8) = v;
        }
    }
}

// ---------------- K6: y = rmsnorm((y + D*x) * silu(z)) * gw ------------------
__global__ __launch_bounds__(256) void gate_norm_kernel(
    const bf16* __restrict__ zx, const float* __restrict__ gw,
    const float* __restrict__ Dvec, const bf16* __restrict__ xBC,
    bf16* __restrict__ y /* zx+2048, lda ZX_C */) {
    int r = blockIdx.x;
    int tid = threadIdx.x;
    float v[8];
    float ss = 0.f;
#pragma unroll
    for (int q = 0; q < 8; ++q) {
        int i = tid + q * 256;
        float z = __bfloat162float(zx[(size_t)r * ZX_C + i]);
        float xv = __bfloat162float(xBC[(size_t)r * XBC_C + i]);
        float val = (__bfloat162float(y[(size_t)r * ZX_C + i]) + Dvec[i >> 6] * xv)
                    * (z / (1.f + __expf(-z)));
        v[q] = val;
        ss += val * val;
    }
    ss = block_reduce_sum(ss);
    float scale = rsqrtf(ss / (float)DI + EPS);
#pragma unroll
    for (int q = 0; q < 8; ++q) {
        int i = tid + q * 256;
        y[(size_t)r * ZX_C + i] = __float2bfloat16(v[q] * scale * gw[i]);
    }
}

// ---------------- launch ----------------
extern "C" void kernel_launch(void* const* d_in, const int* in_sizes, int n_in,
                              void* d_out, int out_size, void* d_ws, size_t ws_size,
                              hipStream_t stream) {
    const float* hid      = (const float*)d_in[0];
    const float* resid    = (const float*)d_in[1];
    const float* norm_w   = (const float*)d_in[2];
    const float* in_proj  = (const float*)d_in[3];
    const float* conv_w   = (const float*)d_in[4];
    const float* conv_b   = (const float*)d_in[5];
    const float* dt_bias  = (const float*)d_in[6];
    const float* A_log    = (const float*)d_in[7];
    const float* Dvec     = (const float*)d_in[8];
    const float* gate_w   = (const float*)d_in[9];
    const float* out_proj = (const float*)d_in[10];

    float* out_p   = (float*)d_out;                  // [8192,1024] f32
    float* res_out = out_p + (size_t)RTOT * DM;      // [8192,1024] f32
    bf16*  h_bf16  = (bf16*)out_p;                   // dead after GEMM1
    float* states  = out_p;                          // 33.55 MB exact fit

    char* wsb = (char*)d_ws;
    bf16*  zx      = (bf16*)wsb;  wsb += (size_t)RTOT * ZX_C * sizeof(bf16);   // 71.8 MB
    bf16*  xBC     = (bf16*)wsb;  wsb += (size_t)RTOT * XBC_C * sizeof(bf16);  // 37.7 MB
    float* dtraw   = (float*)wsb; wsb += (size_t)RTOT * 32 * sizeof(float);
    float* dt_bh   = (float*)wsb; wsb += (size_t)BATCH * NH * LQ * sizeof(float);
    float* Acum_bh = (float*)wsb; wsb += (size_t)BATCH * NH * LQ * sizeof(float);
    bf16* Bt1 = xBC;      // aliases xBC region (dead at those times)
    bf16* Bt2 = xBC;

    transpose_to_bf16_kernel<<<dim3(NP1 / 32, DM / 32), 256, 0, stream>>>(
        in_proj, Bt1, DM, ZX_C);
    add_rmsnorm_kernel<<<RTOT, 256, 0, stream>>>(hid, resid, norm_w, res_out, h_bf16);
    gemm_mfma_kernel<0><<<dim3(NP1 / 128, RTOT / 128), 256, 0, stream>>>(
        h_bf16, DM, Bt1, zx, ZX_C, RTOT, ZX_C, DM, dtraw);
    conv_silu_kernel<<<(RTOT * XBC_C) / 256, 256, 0, stream>>>(
        zx, conv_w, conv_b, xBC);
    dt_scan_kernel<<<BATCH * NH * NC, 256, 0, stream>>>(
        dtraw, dt_bias, A_log, dt_bh, Acum_bh);
    states_kernel<<<BATCH * NH * NC, 256, 0, stream>>>(
        xBC, dt_bh, Acum_bh, states);
    chunk_scan_kernel<<<BATCH * NH, 256, 0, stream>>>(states, Acum_bh);
    y_mfma_kernel<<<BATCH * NH * NC, 256, 0, stream>>>(
        xBC, dt_bh, Acum_bh, states, zx + DI);
    // gate_norm BEFORE Bt2 transpose: it reads xBC (D*x term); Bt2 aliases xBC.
    gate_norm_kernel<<<RTOT, 256, 0, stream>>>(zx, gate_w, Dvec, xBC, zx + DI);
    transpose_to_bf16_kernel<<<dim3(DM / 32, DI / 32), 256, 0, stream>>>(
        out_proj, Bt2, DI, DM);
    gemm_mfma_kernel<1><<<dim3(DM / 128, RTOT / 128), 256, 0, stream>>>(
        zx + DI, ZX_C, Bt2, out_p, DM, RTOT, DM, DI, nullptr);
}

// Round 7
// 575.820 us; speedup vs baseline: 4.2210x; 1.2016x over previous
//
#include <hip/hip_runtime.h>
#include <hip/hip_bf16.h>
#include <math.h>

// ---------------- geometry ----------------
#define BATCH   2
#define LQ      4096            // seqlen
#define RTOT    8192            // BATCH*LQ rows
#define DM      1024            // d_model
#define DI      2048            // d_inner
#define NH      32              // heads
#define HD      64              // head dim p
#define DS      128             // d_state n
#define CH      256             // chunk
#define NC      16              // chunks per seq
#define XBC_C   2304            // conv channels
#define ZX_C    4384            // in_proj output cols
#define NP1     4480            // padded N for gemm1 B^T (35*128)
#define EPS     1e-5f
#define LOG2E   1.4426950408889634f

typedef __hip_bfloat16 bf16;
typedef __bf16 bf16x8v __attribute__((ext_vector_type(8)));
typedef __bf16 bf16x4v __attribute__((ext_vector_type(4)));
typedef float f32x4v __attribute__((ext_vector_type(4)));

// ---------------- block reduce ----------------
__device__ __forceinline__ float block_reduce_sum(float v) {
    __shared__ float sred[8];
    int lane = threadIdx.x & 63, w = threadIdx.x >> 6;
#pragma unroll
    for (int off = 32; off > 0; off >>= 1) v += __shfl_down(v, off, 64);
    if (lane == 0) sred[w] = v;
    __syncthreads();
    float t = (threadIdx.x < (int)(blockDim.x >> 6)) ? sred[threadIdx.x] : 0.f;
    if (w == 0) {
#pragma unroll
        for (int off = 4; off > 0; off >>= 1) t += __shfl_down(t, off, 64);
        if (lane == 0) sred[0] = t;
    }
    __syncthreads();
    return sred[0];
}

// ---------------- K0: W[K][N] f32 -> WT[NP][K] bf16 (zero-pad n>=N) ----------
__global__ __launch_bounds__(256) void transpose_to_bf16_kernel(
    const float* __restrict__ W, bf16* __restrict__ WT, int K, int N) {
    __shared__ float t[32][33];
    int n0 = blockIdx.x * 32, k0 = blockIdx.y * 32;
    int tx = threadIdx.x & 31, ty = threadIdx.x >> 5;   // 32 x 8
#pragma unroll
    for (int r = 0; r < 32; r += 8) {
        int k = k0 + ty + r, n = n0 + tx;
        t[ty + r][tx] = (n < N) ? W[(size_t)k * N + n] : 0.f;
    }
    __syncthreads();
#pragma unroll
    for (int r = 0; r < 32; r += 8) {
        int n = n0 + ty + r, k = k0 + tx;
        WT[(size_t)n * K + k] = __float2bfloat16(t[tx][ty + r]);
    }
}

// ---------------- K1: res = hid + residual; h = rmsnorm(res)*w (bf16) --------
__global__ __launch_bounds__(256) void add_rmsnorm_kernel(
    const float* __restrict__ hid, const float* __restrict__ resid,
    const float* __restrict__ w, float* __restrict__ res_out,
    bf16* __restrict__ h_out) {
    int r = blockIdx.x;
    int tid = threadIdx.x;
    size_t base = (size_t)r * DM;
    float4 hv = *(const float4*)&hid[base + tid * 4];
    float4 rv = *(const float4*)&resid[base + tid * 4];
    float4 s = {hv.x + rv.x, hv.y + rv.y, hv.z + rv.z, hv.w + rv.w};
    *(float4*)&res_out[base + tid * 4] = s;
    float ss = s.x * s.x + s.y * s.y + s.z * s.z + s.w * s.w;
    ss = block_reduce_sum(ss);
    float scale = rsqrtf(ss / (float)DM + EPS);
    float4 wv = *(const float4*)&w[tid * 4];
    __hip_bfloat162 p0, p1;
    p0.x = __float2bfloat16(s.x * scale * wv.x);
    p0.y = __float2bfloat16(s.y * scale * wv.y);
    p1.x = __float2bfloat16(s.z * scale * wv.z);
    p1.y = __float2bfloat16(s.w * scale * wv.w);
    bf16* hp = &h_out[base + tid * 4];
    *(__hip_bfloat162*)hp = p0;
    *(__hip_bfloat162*)(hp + 2) = p1;
}

// ---------------- MFMA GEMM: C[M,N] = A[M,K](bf16,lda) @ Bt[Npad,K]^T --------
template <int WRITE_F32>
__global__ __launch_bounds__(256) void gemm_mfma_kernel(
    const bf16* __restrict__ A, int lda, const bf16* __restrict__ Bt,
    void* __restrict__ C, int ldc, int M, int N, int K,
    float* __restrict__ dtraw) {
    __shared__ __align__(16) bf16 As[128 * 32];
    __shared__ __align__(16) bf16 Bs[128 * 32];
    int tid = threadIdx.x;
    int lane = tid & 63, wave = tid >> 6;
    int wm = (wave >> 1) * 64, wn = (wave & 1) * 64;
    int m0 = blockIdx.y * 128, n0 = blockIdx.x * 128;
    int fr = lane & 15, kg = lane >> 4;

    int off0 = tid * 16, off1 = off0 + 4096;
    int row0 = off0 >> 6, colb0 = off0 & 63;
    int row1 = off1 >> 6, colb1 = off1 & 63;
    const bf16* ga0 = A + (size_t)(m0 + row0) * lda + (colb0 >> 1);
    const bf16* ga1 = A + (size_t)(m0 + row1) * lda + (colb1 >> 1);
    const bf16* gb0 = Bt + (size_t)(n0 + row0) * K + (colb0 >> 1);
    const bf16* gb1 = Bt + (size_t)(n0 + row1) * K + (colb1 >> 1);

    f32x4v acc[4][4] = {};
    for (int k0 = 0; k0 < K; k0 += 32) {
        __syncthreads();
        __builtin_amdgcn_global_load_lds(
            (const __attribute__((address_space(1))) void*)(ga0 + k0),
            (__attribute__((address_space(3))) void*)((char*)As + off0), 16, 0, 0);
        __builtin_amdgcn_global_load_lds(
            (const __attribute__((address_space(1))) void*)(ga1 + k0),
            (__attribute__((address_space(3))) void*)((char*)As + off1), 16, 0, 0);
        __builtin_amdgcn_global_load_lds(
            (const __attribute__((address_space(1))) void*)(gb0 + k0),
            (__attribute__((address_space(3))) void*)((char*)Bs + off0), 16, 0, 0);
        __builtin_amdgcn_global_load_lds(
            (const __attribute__((address_space(1))) void*)(gb1 + k0),
            (__attribute__((address_space(3))) void*)((char*)Bs + off1), 16, 0, 0);
        __syncthreads();
        bf16x8v af[4], bfv[4];
#pragma unroll
        for (int mt = 0; mt < 4; ++mt)
            af[mt] = *(const bf16x8v*)&As[(wm + mt * 16 + fr) * 32 + kg * 8];
#pragma unroll
        for (int nt = 0; nt < 4; ++nt)
            bfv[nt] = *(const bf16x8v*)&Bs[(wn + nt * 16 + fr) * 32 + kg * 8];
#pragma unroll
        for (int mt = 0; mt < 4; ++mt)
#pragma unroll
            for (int nt = 0; nt < 4; ++nt)
                acc[mt][nt] = __builtin_amdgcn_mfma_f32_16x16x32_bf16(
                    af[mt], bfv[nt], acc[mt][nt], 0, 0, 0);
    }
    int col = lane & 15, rbase = (lane >> 4) * 4;
#pragma unroll
    for (int mt = 0; mt < 4; ++mt) {
#pragma unroll
        for (int nt = 0; nt < 4; ++nt) {
            int gn = n0 + wn + nt * 16 + col;
            if (gn >= N) continue;
#pragma unroll
            for (int rg = 0; rg < 4; ++rg) {
                int gm = m0 + wm + mt * 16 + rbase + rg;
                float v = acc[mt][nt][rg];
                if (WRITE_F32) {
                    ((float*)C)[(size_t)gm * ldc + gn] = v;
                } else {
                    ((bf16*)C)[(size_t)gm * ldc + gn] = __float2bfloat16(v);
                    if (dtraw && gn >= 4352)
                        dtraw[(size_t)gm * 32 + (gn - 4352)] = v;
                }
            }
        }
    }
}

// ---------------- K3: depthwise causal conv(4) + bias + SiLU (bf16x8) -------
__global__ __launch_bounds__(256) void conv_silu_kernel(
    const bf16* __restrict__ zx, const float* __restrict__ conv_w,
    const float* __restrict__ conv_b, bf16* __restrict__ xBC) {
    int idx = blockIdx.x * 256 + threadIdx.x;       // RTOT*288 total
    int r = idx / 288;
    int o = idx - r * 288;
    int c = o * 8;
    int b = r >> 12, l = r & (LQ - 1);
    float acc[8];
    {
        float4 cb0 = *(const float4*)&conv_b[c];
        float4 cb1 = *(const float4*)&conv_b[c + 4];
        acc[0] = cb0.x; acc[1] = cb0.y; acc[2] = cb0.z; acc[3] = cb0.w;
        acc[4] = cb1.x; acc[5] = cb1.y; acc[6] = cb1.z; acc[7] = cb1.w;
    }
#pragma unroll
    for (int k = 0; k < 4; ++k) {
        int t = l - 3 + k;
        if (t >= 0) {
            bf16x8v xv = *(const bf16x8v*)&zx[(size_t)(b * LQ + t) * ZX_C + DI + c];
            float4 w0 = *(const float4*)&conv_w[k * XBC_C + c];
            float4 w1 = *(const float4*)&conv_w[k * XBC_C + c + 4];
            acc[0] = fmaf(w0.x, (float)xv[0], acc[0]);
            acc[1] = fmaf(w0.y, (float)xv[1], acc[1]);
            acc[2] = fmaf(w0.z, (float)xv[2], acc[2]);
            acc[3] = fmaf(w0.w, (float)xv[3], acc[3]);
            acc[4] = fmaf(w1.x, (float)xv[4], acc[4]);
            acc[5] = fmaf(w1.y, (float)xv[5], acc[5]);
            acc[6] = fmaf(w1.z, (float)xv[6], acc[6]);
            acc[7] = fmaf(w1.w, (float)xv[7], acc[7]);
        }
    }
    bf16x8v ov;
#pragma unroll
    for (int j = 0; j < 8; ++j)
        ov[j] = (__bf16)(acc[j] / (1.f + __expf(-acc[j])));
    *(bf16x8v*)&xBC[(size_t)r * XBC_C + c] = ov;
}

// ---------------- K3b: dt = softplus(dt_raw+bias); chunk cumsum of dt*A*log2e
__global__ __launch_bounds__(256) void dt_scan_kernel(
    const float* __restrict__ dtraw, const float* __restrict__ dt_bias,
    const float* __restrict__ A_log, float* __restrict__ dt_bh,
    float* __restrict__ Ac2_bh) {
    __shared__ float sA[256];
    int bid = blockIdx.x;                       // (b,h,c)
    int c = bid & 15, h = (bid >> 4) & 31, b = bid >> 9;
    int tid = threadIdx.x;
    int l = c * CH + tid;
    int r = b * LQ + l;
    float v = dtraw[(size_t)r * 32 + h] + dt_bias[h];
    float dt = (v > 20.f) ? v : log1pf(expf(v));
    float A = -expf(A_log[h]);
    sA[tid] = dt * A * LOG2E;                   // log2-units cumulative decay
    __syncthreads();
    for (int off = 1; off < 256; off <<= 1) {
        float t = (tid >= off) ? sA[tid - off] : 0.f;
        __syncthreads();
        sA[tid] += t;
        __syncthreads();
    }
    size_t o = (size_t)(b * NH + h) * LQ + l;
    dt_bh[o] = dt;
    Ac2_bh[o] = sA[tid];
}

// ---------------- K4a (MFMA): states[p,n] = sum_l xdtd[l,p] * B[l,n] --------
// xdtd[l,p] = x[l,p]*dt[l]*2^(Ac2[last]-Ac2[l]).  D[m=p][n'=n], k=l.
__global__ __launch_bounds__(256) void states_mfma_kernel(
    const bf16* __restrict__ xBC, const float* __restrict__ dt_bh,
    const float* __restrict__ Ac2, float* __restrict__ states) {
    __shared__ __align__(16) __bf16 xdT[64][264];    // [p][l]
    __shared__ __align__(16) __bf16 BT[64][264];     // [n_loc][l], per n-half
    int bid = blockIdx.x;                          // (b,h,c)
    int c = bid & 15, h = (bid >> 4) & 31, b = bid >> 9;
    int bh = b * NH + h;
    int rch = b * LQ + c * CH;
    int tid = threadIdx.x;
    int wave = tid >> 6, lane = tid & 63;
    int fr = lane & 15, kg = lane >> 4;
    float Ac2last = Ac2[(size_t)bh * LQ + c * CH + (CH - 1)];

    {   // build xdT[p][l]
        int p2 = (tid & 31) * 2;
        int srow = tid >> 5;
#pragma unroll 4
        for (int pass = 0; pass < 32; ++pass) {
            int s = pass * 8 + srow;
            float sc = dt_bh[(size_t)bh * LQ + c * CH + s] *
                       exp2f(Ac2last - Ac2[(size_t)bh * LQ + c * CH + s]);
            __hip_bfloat162 xv =
                *(const __hip_bfloat162*)&xBC[(size_t)(rch + s) * XBC_C + h * HD + p2];
            xdT[p2][s]     = (__bf16)(__bfloat162float(xv.x) * sc);
            xdT[p2 + 1][s] = (__bf16)(__bfloat162float(xv.y) * sc);
        }
    }
    int wm = (wave >> 1) * 32, wn = (wave & 1) * 32;
    size_t base = (size_t)(bh * NC + c) * HD * DS;
    for (int nh = 0; nh < 2; ++nh) {
        __syncthreads();   // xdT ready (iter0) / prior BT reads done (iter1)
        {   // build BT[n_loc][l] = B[l][nh*64 + n_loc]
            int n_oct = tid & 7, lrow = tid >> 3;      // 32 l-rows per pass
#pragma unroll
            for (int pass = 0; pass < 8; ++pass) {
                int l = pass * 32 + lrow;
                bf16x8v bv = *(const bf16x8v*)
                    &xBC[(size_t)(rch + l) * XBC_C + DI + nh * 64 + n_oct * 8];
#pragma unroll
                for (int j = 0; j < 8; ++j)
                    BT[n_oct * 8 + j][l] = bv[j];
            }
        }
        __syncthreads();
        f32x4v acc[2][2] = {};
#pragma unroll
        for (int kb = 0; kb < 8; ++kb) {
            bf16x8v A2[2], B2[2];
#pragma unroll
            for (int i = 0; i < 2; ++i)
                A2[i] = *(const bf16x8v*)&xdT[wm + i * 16 + fr][kb * 32 + kg * 8];
#pragma unroll
            for (int j = 0; j < 2; ++j)
                B2[j] = *(const bf16x8v*)&BT[wn + j * 16 + fr][kb * 32 + kg * 8];
#pragma unroll
            for (int i = 0; i < 2; ++i)
#pragma unroll
                for (int j = 0; j < 2; ++j)
                    acc[i][j] = __builtin_amdgcn_mfma_f32_16x16x32_bf16(
                        A2[i], B2[j], acc[i][j], 0, 0, 0);
        }
#pragma unroll
        for (int i = 0; i < 2; ++i)
#pragma unroll
            for (int j = 0; j < 2; ++j)
#pragma unroll
                for (int rg = 0; rg < 4; ++rg) {
                    int p = wm + i * 16 + kg * 4 + rg;
                    int n = nh * 64 + wn + j * 16 + fr;
                    states[base + (size_t)p * DS + n] = acc[i][j][rg];
                }
    }
}

// ---------------- K5: inter-chunk scan, in place ------------------------------
__global__ __launch_bounds__(256) void chunk_scan_kernel(
    float* __restrict__ states, const float* __restrict__ Ac2) {
    int bh = blockIdx.x;
    int tid = threadIdx.x;
    float carry[32];
#pragma unroll
    for (int j = 0; j < 32; ++j) carry[j] = 0.f;
    for (int c = 0; c < NC; ++c) {
        float dec = exp2f(Ac2[(size_t)bh * LQ + c * CH + (CH - 1)]);
        size_t base = (size_t)(bh * NC + c) * (HD * DS);
#pragma unroll
        for (int j = 0; j < 32; ++j) {
            size_t idx = base + tid + j * 256;
            float tmp = states[idx];
            states[idx] = carry[j];
            carry[j] = carry[j] * dec + tmp;
        }
    }
}

// ---------------- K4b (MFMA): Y = (C·B^T ∘ L)·xdt + 2^Ac2·(C·prev^T) ---------
// One block per (b,h,c); wave w owns l-strip [w*64, w*64+64).
// P processed in 32-s half-slabs (LDS 52 KB -> 3 blocks/CU).
__global__ __launch_bounds__(256) void y_mfma_kernel(
    const bf16* __restrict__ xBC, const float* __restrict__ dt_bh,
    const float* __restrict__ Ac2, const float* __restrict__ prev,
    bf16* __restrict__ yout /* zx+2048, stride ZX_C */) {
    __shared__ __align__(16) __bf16 xdtT[64][264];   // [p][s]
    __shared__ __align__(16) __bf16 P[4][64][36];    // per-wave, 32-s half slab
    __shared__ float As_sh[256];
    int bid = blockIdx.x;
    int c = bid & 15, h = (bid >> 4) & 31, b = bid >> 9;
    int bh = b * NH + h;
    int rch = b * LQ + c * CH;
    int tid = threadIdx.x;
    int wave = tid >> 6, lane = tid & 63;
    int fr = lane & 15, kg = lane >> 4;

    As_sh[tid] = Ac2[(size_t)bh * LQ + c * CH + tid];
    {   // xdtT[p][s] = x[s][p] * dt[s]
        int p2 = (tid & 31) * 2;
        int srow = tid >> 5;
#pragma unroll 4
        for (int pass = 0; pass < 32; ++pass) {
            int s = pass * 8 + srow;
            float dtv = dt_bh[(size_t)bh * LQ + c * CH + s];
            __hip_bfloat162 xv =
                *(const __hip_bfloat162*)&xBC[(size_t)(rch + s) * XBC_C + h * HD + p2];
            xdtT[p2][s]     = (__bf16)(__bfloat162float(xv.x) * dtv);
            xdtT[p2 + 1][s] = (__bf16)(__bfloat162float(xv.y) * dtv);
        }
    }
    __syncthreads();

    // cache C A-fragments for this wave's strip: [mt][ks]
    bf16x8v CA[4][4];
    {
        size_t rb = (size_t)(rch + wave * 64 + fr) * XBC_C + DI + DS + kg * 8;
#pragma unroll
        for (int mt = 0; mt < 4; ++mt)
#pragma unroll
            for (int ks = 0; ks < 4; ++ks)
                CA[mt][ks] = *(const bf16x8v*)&xBC[rb + (size_t)mt * 16 * XBC_C + ks * 32];
    }

    f32x4v accY[4][4] = {};    // [mt][pt], D-layout

    // off-diagonal: C · prev^T
    {
        size_t pbase = (size_t)(bh * NC + c) * HD * DS;
#pragma unroll
        for (int ks = 0; ks < 4; ++ks) {
            bf16x8v PB[4];
#pragma unroll
            for (int pt = 0; pt < 4; ++pt) {
                const float* pp = &prev[pbase + (size_t)(pt * 16 + fr) * DS + ks * 32 + kg * 8];
                float4 a4 = *(const float4*)pp;
                float4 b4 = *(const float4*)(pp + 4);
                bf16x8v t;
                t[0] = (__bf16)a4.x; t[1] = (__bf16)a4.y; t[2] = (__bf16)a4.z; t[3] = (__bf16)a4.w;
                t[4] = (__bf16)b4.x; t[5] = (__bf16)b4.y; t[6] = (__bf16)b4.z; t[7] = (__bf16)b4.w;
                PB[pt] = t;
            }
#pragma unroll
            for (int mt = 0; mt < 4; ++mt)
#pragma unroll
                for (int pt = 0; pt < 4; ++pt)
                    accY[mt][pt] = __builtin_amdgcn_mfma_f32_16x16x32_bf16(
                        CA[mt][ks], PB[pt], accY[mt][pt], 0, 0, 0);
        }
    }
    int l0 = wave * 64;
    float eAl[4][4];           // 2^Ac2[l] per [mt][rg]
#pragma unroll
    for (int mt = 0; mt < 4; ++mt)
#pragma unroll
        for (int rg = 0; rg < 4; ++rg)
            eAl[mt][rg] = exp2f(As_sh[l0 + mt * 16 + kg * 4 + rg]);
#pragma unroll
    for (int mt = 0; mt < 4; ++mt)
#pragma unroll
        for (int pt = 0; pt < 4; ++pt)
#pragma unroll
            for (int rg = 0; rg < 4; ++rg)
                accY[mt][pt][rg] *= eAl[mt][rg];

    // triangular diag part: st = 0..wave (no block barriers inside)
    for (int st = 0; st <= wave; ++st) {
        int s0 = st * 64;
#pragma unroll
        for (int half = 0; half < 2; ++half) {
            f32x4v Sacc[4][2] = {};
#pragma unroll
            for (int ks = 0; ks < 4; ++ks) {
                bf16x8v SB[2];
#pragma unroll
                for (int nh2 = 0; nh2 < 2; ++nh2) {
                    int nt = half * 2 + nh2;
                    SB[nh2] = *(const bf16x8v*)
                        &xBC[(size_t)(rch + s0 + nt * 16 + fr) * XBC_C + DI + ks * 32 + kg * 8];
                }
#pragma unroll
                for (int mt = 0; mt < 4; ++mt)
#pragma unroll
                    for (int nh2 = 0; nh2 < 2; ++nh2)
                        Sacc[mt][nh2] = __builtin_amdgcn_mfma_f32_16x16x32_bf16(
                            CA[mt][ks], SB[nh2], Sacc[mt][nh2], 0, 0, 0);
            }
            // mask + decay, write P half (cols 0..31)
#pragma unroll
            for (int mt = 0; mt < 4; ++mt) {
#pragma unroll
                for (int nh2 = 0; nh2 < 2; ++nh2) {
                    int nt = half * 2 + nh2;
                    int s_loc = s0 + nt * 16 + fr;
#pragma unroll
                    for (int rg = 0; rg < 4; ++rg) {
                        int l_loc = mt * 16 + kg * 4 + rg;
                        int l_idx = l0 + l_loc;
                        float v = 0.f;
                        if (s_loc <= l_idx)
                            v = Sacc[mt][nh2][rg] * exp2f(As_sh[l_idx] - As_sh[s_loc]);
                        P[wave][l_loc][nh2 * 16 + fr] = (__bf16)v;
                    }
                }
            }
            __asm__ volatile("s_waitcnt lgkmcnt(0)" ::: "memory");
            // Y += P_half · xdt (s-range [s0+half*32, +32))
            bf16x8v PA[4], XB[4];
#pragma unroll
            for (int mt = 0; mt < 4; ++mt) {
                bf16x4v plo = *(const bf16x4v*)&P[wave][mt * 16 + fr][kg * 8];
                bf16x4v phi = *(const bf16x4v*)&P[wave][mt * 16 + fr][kg * 8 + 4];
                bf16x8v pa;
#pragma unroll
                for (int j = 0; j < 4; ++j) { pa[j] = plo[j]; pa[4 + j] = phi[j]; }
                PA[mt] = pa;
            }
#pragma unroll
            for (int pt = 0; pt < 4; ++pt)
                XB[pt] = *(const bf16x8v*)&xdtT[pt * 16 + fr][s0 + half * 32 + kg * 8];
#pragma unroll
            for (int mt = 0; mt < 4; ++mt)
#pragma unroll
                for (int pt = 0; pt < 4; ++pt)
                    accY[mt][pt] = __builtin_amdgcn_mfma_f32_16x16x32_bf16(
                        PA[mt], XB[pt], accY[mt][pt], 0, 0, 0);
        }
    }

    // epilogue: two 32-col passes staged through P for coalesced stores
#pragma unroll
    for (int ph = 0; ph < 2; ++ph) {
#pragma unroll
        for (int mt = 0; mt < 4; ++mt)
#pragma unroll
            for (int ptl = 0; ptl < 2; ++ptl)
#pragma unroll
                for (int rg = 0; rg < 4; ++rg)
                    P[wave][mt * 16 + kg * 4 + rg][ptl * 16 + fr] =
                        (__bf16)accY[mt][ph * 2 + ptl][rg];
        __asm__ volatile("s_waitcnt lgkmcnt(0)" ::: "memory");
        bf16* yp = yout + (size_t)(rch + l0 + lane) * ZX_C + h * HD + ph * 32;
#pragma unroll
        for (int q = 0; q < 4; ++q) {
            bf16x4v a = *(const bf16x4v*)&P[wave][lane][q * 8];
            bf16x4v bq = *(const bf16x4v*)&P[wave][lane][q * 8 + 4];
            bf16x8v v;
#pragma unroll
            for (int j = 0; j < 4; ++j) { v[j] = a[j]; v[4 + j] = bq[j]; }
            *(bf16x8v*)(yp + q * 8) = v;
        }
        __asm__ volatile("s_waitcnt lgkmcnt(0)" ::: "memory");
    }
}

// ---------------- K6: y = rmsnorm((y + D*x) * silu(z)) * gw (bf16x8) ---------
__global__ __launch_bounds__(256) void gate_norm_kernel(
    const bf16* __restrict__ zx, const float* __restrict__ gw,
    const float* __restrict__ Dvec, const bf16* __restrict__ xBC,
    bf16* __restrict__ y /* zx+2048, lda ZX_C */) {
    int r = blockIdx.x;
    int tid = threadIdx.x;
    int i0 = tid * 8;
    bf16x8v zv = *(const bf16x8v*)&zx[(size_t)r * ZX_C + i0];
    bf16x8v yv = *(const bf16x8v*)&y[(size_t)r * ZX_C + i0];
    bf16x8v xv = *(const bf16x8v*)&xBC[(size_t)r * XBC_C + i0];
    float Dh = Dvec[tid >> 3];
    float v[8];
    float ss = 0.f;
#pragma unroll
    for (int j = 0; j < 8; ++j) {
        float z = (float)zv[j];
        float val = ((float)yv[j] + Dh * (float)xv[j]) * (z / (1.f + __expf(-z)));
        v[j] = val;
        ss += val * val;
    }
    ss = block_reduce_sum(ss);
    float scale = rsqrtf(ss / (float)DI + EPS);
    float4 g0 = *(const float4*)&gw[i0];
    float4 g1 = *(const float4*)&gw[i0 + 4];
    float g[8] = {g0.x, g0.y, g0.z, g0.w, g1.x, g1.y, g1.z, g1.w};
    bf16x8v ov;
#pragma unroll
    for (int j = 0; j < 8; ++j)
        ov[j] = (__bf16)(v[j] * scale * g[j]);
    *(bf16x8v*)&y[(size_t)r * ZX_C + i0] = ov;
}

// ---------------- launch ----------------
extern "C" void kernel_launch(void* const* d_in, const int* in_sizes, int n_in,
                              void* d_out, int out_size, void* d_ws, size_t ws_size,
                              hipStream_t stream) {
    const float* hid      = (const float*)d_in[0];
    const float* resid    = (const float*)d_in[1];
    const float* norm_w   = (const float*)d_in[2];
    const float* in_proj  = (const float*)d_in[3];
    const float* conv_w   = (const float*)d_in[4];
    const float* conv_b   = (const float*)d_in[5];
    const float* dt_bias  = (const float*)d_in[6];
    const float* A_log    = (const float*)d_in[7];
    const float* Dvec     = (const float*)d_in[8];
    const float* gate_w   = (const float*)d_in[9];
    const float* out_proj = (const float*)d_in[10];

    float* out_p   = (float*)d_out;                  // [8192,1024] f32
    float* res_out = out_p + (size_t)RTOT * DM;      // [8192,1024] f32
    bf16*  h_bf16  = (bf16*)out_p;                   // dead after GEMM1
    float* states  = out_p;                          // 33.55 MB exact fit

    char* wsb = (char*)d_ws;
    bf16*  zx      = (bf16*)wsb;  wsb += (size_t)RTOT * ZX_C * sizeof(bf16);   // 71.8 MB
    bf16*  xBC     = (bf16*)wsb;  wsb += (size_t)RTOT * XBC_C * sizeof(bf16);  // 37.7 MB
    float* dtraw   = (float*)wsb; wsb += (size_t)RTOT * 32 * sizeof(float);
    float* dt_bh   = (float*)wsb; wsb += (size_t)BATCH * NH * LQ * sizeof(float);
    float* Ac2_bh  = (float*)wsb; wsb += (size_t)BATCH * NH * LQ * sizeof(float);
    bf16* Bt1 = xBC;      // aliases xBC region (dead at those times)
    bf16* Bt2 = xBC;

    transpose_to_bf16_kernel<<<dim3(NP1 / 32, DM / 32), 256, 0, stream>>>(
        in_proj, Bt1, DM, ZX_C);
    add_rmsnorm_kernel<<<RTOT, 256, 0, stream>>>(hid, resid, norm_w, res_out, h_bf16);
    gemm_mfma_kernel<0><<<dim3(NP1 / 128, RTOT / 128), 256, 0, stream>>>(
        h_bf16, DM, Bt1, zx, ZX_C, RTOT, ZX_C, DM, dtraw);
    conv_silu_kernel<<<(RTOT * 288) / 256, 256, 0, stream>>>(
        zx, conv_w, conv_b, xBC);
    dt_scan_kernel<<<BATCH * NH * NC, 256, 0, stream>>>(
        dtraw, dt_bias, A_log, dt_bh, Ac2_bh);
    states_mfma_kernel<<<BATCH * NH * NC, 256, 0, stream>>>(
        xBC, dt_bh, Ac2_bh, states);
    chunk_scan_kernel<<<BATCH * NH, 256, 0, stream>>>(states, Ac2_bh);
    y_mfma_kernel<<<BATCH * NH * NC, 256, 0, stream>>>(
        xBC, dt_bh, Ac2_bh, states, zx + DI);
    // gate_norm BEFORE Bt2 transpose: it reads xBC (D*x term); Bt2 aliases xBC.
    gate_norm_kernel<<<RTOT, 256, 0, stream>>>(zx, gate_w, Dvec, xBC, zx + DI);
    transpose_to_bf16_kernel<<<dim3(DM / 32, DI / 32), 256, 0, stream>>>(
        out_proj, Bt2, DI, DM);
    gemm_mfma_kernel<1><<<dim3(DM / 128, RTOT / 128), 256, 0, stream>>>(
        zx + DI, ZX_C, Bt2, out_p, DM, RTOT, DM, DI, nullptr);
}

// Round 8
// 528.251 us; speedup vs baseline: 4.6011x; 1.0900x over previous
//
#include <hip/hip_runtime.h>
#include <hip/hip_bf16.h>
#include <math.h>

// ---------------- geometry ----------------
#define BATCH   2
#define LQ      4096            // seqlen
#define RTOT    8192            // BATCH*LQ rows
#define DM      1024            // d_model
#define DI      2048            // d_inner
#define NH      32              // heads
#define HD      64              // head dim p
#define DS      128             // d_state n
#define CH      256             // chunk
#define NC      16              // chunks per seq
#define XBC_C   2304            // conv channels
#define ZX_C    4384            // in_proj logical output cols
#define ZXS     4352            // zx row stride (dt cols live only in dtraw)
#define NP1     4480            // padded N for gemm1 B^T (35*128)
#define EPS     1e-5f
#define LOG2E   1.4426950408889634f

typedef __hip_bfloat16 bf16;
typedef __bf16 bf16x8v __attribute__((ext_vector_type(8)));
typedef __bf16 bf16x4v __attribute__((ext_vector_type(4)));
typedef float f32x4v __attribute__((ext_vector_type(4)));

// ---------------- block reduce ----------------
__device__ __forceinline__ float block_reduce_sum(float v) {
    __shared__ float sred[8];
    int lane = threadIdx.x & 63, w = threadIdx.x >> 6;
#pragma unroll
    for (int off = 32; off > 0; off >>= 1) v += __shfl_down(v, off, 64);
    if (lane == 0) sred[w] = v;
    __syncthreads();
    float t = (threadIdx.x < (int)(blockDim.x >> 6)) ? sred[threadIdx.x] : 0.f;
    if (w == 0) {
#pragma unroll
        for (int off = 4; off > 0; off >>= 1) t += __shfl_down(t, off, 64);
        if (lane == 0) sred[0] = t;
    }
    __syncthreads();
    return sred[0];
}

__device__ __forceinline__ void transpose_tile(
    const float* __restrict__ W, bf16* __restrict__ WT, int K, int N,
    int n0, int k0) {
    __shared__ float t[32][33];
    int tx = threadIdx.x & 31, ty = threadIdx.x >> 5;   // 32 x 8
#pragma unroll
    for (int r = 0; r < 32; r += 8) {
        int k = k0 + ty + r, n = n0 + tx;
        t[ty + r][tx] = (n < N) ? W[(size_t)k * N + n] : 0.f;
    }
    __syncthreads();
#pragma unroll
    for (int r = 0; r < 32; r += 8) {
        int n = n0 + ty + r, k = k0 + tx;
        WT[(size_t)n * K + k] = __float2bfloat16(t[tx][ty + r]);
    }
}

// ---------------- F1: add+rmsnorm rows, plus in_proj transpose tiles ---------
__global__ __launch_bounds__(256) void fused_pre_kernel(
    const float* __restrict__ hid, const float* __restrict__ resid,
    const float* __restrict__ w, float* __restrict__ res_out,
    bf16* __restrict__ h_out, const float* __restrict__ in_proj,
    bf16* __restrict__ Bt1) {
    int bid = blockIdx.x;
    if (bid < RTOT) {
        int r = bid, tid = threadIdx.x;
        size_t base = (size_t)r * DM;
        float4 hv = *(const float4*)&hid[base + tid * 4];
        float4 rv = *(const float4*)&resid[base + tid * 4];
        float4 s = {hv.x + rv.x, hv.y + rv.y, hv.z + rv.z, hv.w + rv.w};
        *(float4*)&res_out[base + tid * 4] = s;
        float ss = s.x * s.x + s.y * s.y + s.z * s.z + s.w * s.w;
        ss = block_reduce_sum(ss);
        float scale = rsqrtf(ss / (float)DM + EPS);
        float4 wv = *(const float4*)&w[tid * 4];
        __hip_bfloat162 p0, p1;
        p0.x = __float2bfloat16(s.x * scale * wv.x);
        p0.y = __float2bfloat16(s.y * scale * wv.y);
        p1.x = __float2bfloat16(s.z * scale * wv.z);
        p1.y = __float2bfloat16(s.w * scale * wv.w);
        bf16* hp = &h_out[base + tid * 4];
        *(__hip_bfloat162*)hp = p0;
        *(__hip_bfloat162*)(hp + 2) = p1;
    } else {
        int t = bid - RTOT;                    // [0, 4480)
        transpose_tile(in_proj, Bt1, DM, ZX_C, (t % 140) * 32, (t / 140) * 32);
    }
}

// ---------------- MFMA GEMM: C[M,N] = A[M,K](bf16,lda) @ Bt[Npad,K]^T --------
template <int WRITE_F32>
__global__ __launch_bounds__(256) void gemm_mfma_kernel(
    const bf16* __restrict__ A, int lda, const bf16* __restrict__ Bt,
    void* __restrict__ C, int ldc, int M, int N, int K,
    float* __restrict__ dtraw) {
    __shared__ __align__(16) bf16 As[128 * 32];
    __shared__ __align__(16) bf16 Bs[128 * 32];
    int tid = threadIdx.x;
    int lane = tid & 63, wave = tid >> 6;
    int wm = (wave >> 1) * 64, wn = (wave & 1) * 64;
    int m0 = blockIdx.y * 128, n0 = blockIdx.x * 128;
    int fr = lane & 15, kg = lane >> 4;

    int off0 = tid * 16, off1 = off0 + 4096;
    int row0 = off0 >> 6, colb0 = off0 & 63;
    int row1 = off1 >> 6, colb1 = off1 & 63;
    const bf16* ga0 = A + (size_t)(m0 + row0) * lda + (colb0 >> 1);
    const bf16* ga1 = A + (size_t)(m0 + row1) * lda + (colb1 >> 1);
    const bf16* gb0 = Bt + (size_t)(n0 + row0) * K + (colb0 >> 1);
    const bf16* gb1 = Bt + (size_t)(n0 + row1) * K + (colb1 >> 1);

    f32x4v acc[4][4] = {};
    for (int k0 = 0; k0 < K; k0 += 32) {
        __syncthreads();
        __builtin_amdgcn_global_load_lds(
            (const __attribute__((address_space(1))) void*)(ga0 + k0),
            (__attribute__((address_space(3))) void*)((char*)As + off0), 16, 0, 0);
        __builtin_amdgcn_global_load_lds(
            (const __attribute__((address_space(1))) void*)(ga1 + k0),
            (__attribute__((address_space(3))) void*)((char*)As + off1), 16, 0, 0);
        __builtin_amdgcn_global_load_lds(
            (const __attribute__((address_space(1))) void*)(gb0 + k0),
            (__attribute__((address_space(3))) void*)((char*)Bs + off0), 16, 0, 0);
        __builtin_amdgcn_global_load_lds(
            (const __attribute__((address_space(1))) void*)(gb1 + k0),
            (__attribute__((address_space(3))) void*)((char*)Bs + off1), 16, 0, 0);
        __syncthreads();
        bf16x8v af[4], bfv[4];
#pragma unroll
        for (int mt = 0; mt < 4; ++mt)
            af[mt] = *(const bf16x8v*)&As[(wm + mt * 16 + fr) * 32 + kg * 8];
#pragma unroll
        for (int nt = 0; nt < 4; ++nt)
            bfv[nt] = *(const bf16x8v*)&Bs[(wn + nt * 16 + fr) * 32 + kg * 8];
#pragma unroll
        for (int mt = 0; mt < 4; ++mt)
#pragma unroll
            for (int nt = 0; nt < 4; ++nt)
                acc[mt][nt] = __builtin_amdgcn_mfma_f32_16x16x32_bf16(
                    af[mt], bfv[nt], acc[mt][nt], 0, 0, 0);
    }
    int col = lane & 15, rbase = (lane >> 4) * 4;
#pragma unroll
    for (int mt = 0; mt < 4; ++mt) {
#pragma unroll
        for (int nt = 0; nt < 4; ++nt) {
            int gn = n0 + wn + nt * 16 + col;
            if (gn >= N) continue;
#pragma unroll
            for (int rg = 0; rg < 4; ++rg) {
                int gm = m0 + wm + mt * 16 + rbase + rg;
                float v = acc[mt][nt][rg];
                if (WRITE_F32) {
                    ((float*)C)[(size_t)gm * ldc + gn] = v;
                } else {
                    if (gn < 4352)
                        ((bf16*)C)[(size_t)gm * ldc + gn] = __float2bfloat16(v);
                    else if (dtraw)
                        dtraw[(size_t)gm * 32 + (gn - 4352)] = v;
                }
            }
        }
    }
}

// ---------------- F2: conv+SiLU blocks, plus dt softplus/cumsum blocks -------
__global__ __launch_bounds__(256) void fused_conv_dt_kernel(
    const bf16* __restrict__ zx, const float* __restrict__ conv_w,
    const float* __restrict__ conv_b, bf16* __restrict__ xBC,
    const float* __restrict__ dtraw, const float* __restrict__ dt_bias,
    const float* __restrict__ A_log, float* __restrict__ dt_bh,
    float* __restrict__ Ac2_bh) {
    int bid = blockIdx.x;
    if (bid < 9216) {
        int idx = bid * 256 + threadIdx.x;       // RTOT*288 total
        int r = idx / 288;
        int o = idx - r * 288;
        int c = o * 8;
        int b = r >> 12, l = r & (LQ - 1);
        float acc[8];
        {
            float4 cb0 = *(const float4*)&conv_b[c];
            float4 cb1 = *(const float4*)&conv_b[c + 4];
            acc[0] = cb0.x; acc[1] = cb0.y; acc[2] = cb0.z; acc[3] = cb0.w;
            acc[4] = cb1.x; acc[5] = cb1.y; acc[6] = cb1.z; acc[7] = cb1.w;
        }
#pragma unroll
        for (int k = 0; k < 4; ++k) {
            int t = l - 3 + k;
            if (t >= 0) {
                bf16x8v xv = *(const bf16x8v*)&zx[(size_t)(b * LQ + t) * ZXS + DI + c];
                float4 w0 = *(const float4*)&conv_w[k * XBC_C + c];
                float4 w1 = *(const float4*)&conv_w[k * XBC_C + c + 4];
                acc[0] = fmaf(w0.x, (float)xv[0], acc[0]);
                acc[1] = fmaf(w0.y, (float)xv[1], acc[1]);
                acc[2] = fmaf(w0.z, (float)xv[2], acc[2]);
                acc[3] = fmaf(w0.w, (float)xv[3], acc[3]);
                acc[4] = fmaf(w1.x, (float)xv[4], acc[4]);
                acc[5] = fmaf(w1.y, (float)xv[5], acc[5]);
                acc[6] = fmaf(w1.z, (float)xv[6], acc[6]);
                acc[7] = fmaf(w1.w, (float)xv[7], acc[7]);
            }
        }
        bf16x8v ov;
#pragma unroll
        for (int j = 0; j < 8; ++j)
            ov[j] = (__bf16)(acc[j] / (1.f + __expf(-acc[j])));
        *(bf16x8v*)&xBC[(size_t)r * XBC_C + c] = ov;
    } else {
        __shared__ float sA[256];
        int b2 = bid - 9216;                    // (b,h,c)
        int c = b2 & 15, h = (b2 >> 4) & 31, b = b2 >> 9;
        int tid = threadIdx.x;
        int l = c * CH + tid;
        int r = b * LQ + l;
        float v = dtraw[(size_t)r * 32 + h] + dt_bias[h];
        float dt = (v > 20.f) ? v : log1pf(expf(v));
        float A = -expf(A_log[h]);
        sA[tid] = dt * A * LOG2E;               // log2-units cumulative decay
        __syncthreads();
        for (int off = 1; off < 256; off <<= 1) {
            float t = (tid >= off) ? sA[tid - off] : 0.f;
            __syncthreads();
            sA[tid] += t;
            __syncthreads();
        }
        size_t o = (size_t)(b * NH + h) * LQ + l;
        dt_bh[o] = dt;
        Ac2_bh[o] = sA[tid];
    }
}

// ---------------- K4a (MFMA): states[p,n] = sum_l xdtd[l,p] * B[l,n] --------
__global__ __launch_bounds__(256) void states_mfma_kernel(
    const bf16* __restrict__ xBC, const float* __restrict__ dt_bh,
    const float* __restrict__ Ac2, float* __restrict__ states) {
    __shared__ __align__(16) __bf16 xdT[64][264];    // [p][l]
    __shared__ __align__(16) __bf16 BT[64][264];     // [n_loc][l], per n-half
    int bid = blockIdx.x;                          // (b,h,c)
    int c = bid & 15, h = (bid >> 4) & 31, b = bid >> 9;
    int bh = b * NH + h;
    int rch = b * LQ + c * CH;
    int tid = threadIdx.x;
    int wave = tid >> 6, lane = tid & 63;
    int fr = lane & 15, kg = lane >> 4;
    float Ac2last = Ac2[(size_t)bh * LQ + c * CH + (CH - 1)];

    {   // build xdT[p][l]
        int p2 = (tid & 31) * 2;
        int srow = tid >> 5;
#pragma unroll 4
        for (int pass = 0; pass < 32; ++pass) {
            int s = pass * 8 + srow;
            float sc = dt_bh[(size_t)bh * LQ + c * CH + s] *
                       exp2f(Ac2last - Ac2[(size_t)bh * LQ + c * CH + s]);
            __hip_bfloat162 xv =
                *(const __hip_bfloat162*)&xBC[(size_t)(rch + s) * XBC_C + h * HD + p2];
            xdT[p2][s]     = (__bf16)(__bfloat162float(xv.x) * sc);
            xdT[p2 + 1][s] = (__bf16)(__bfloat162float(xv.y) * sc);
        }
    }
    int wm = (wave >> 1) * 32, wn = (wave & 1) * 32;
    size_t base = (size_t)(bh * NC + c) * HD * DS;
    for (int nh = 0; nh < 2; ++nh) {
        __syncthreads();   // xdT ready (iter0) / prior BT reads done (iter1)
        {   // build BT[n_loc][l] = B[l][nh*64 + n_loc]
            int n_oct = tid & 7, lrow = tid >> 3;      // 32 l-rows per pass
#pragma unroll
            for (int pass = 0; pass < 8; ++pass) {
                int l = pass * 32 + lrow;
                bf16x8v bv = *(const bf16x8v*)
                    &xBC[(size_t)(rch + l) * XBC_C + DI + nh * 64 + n_oct * 8];
#pragma unroll
                for (int j = 0; j < 8; ++j)
                    BT[n_oct * 8 + j][l] = bv[j];
            }
        }
        __syncthreads();
        f32x4v acc[2][2] = {};
#pragma unroll
        for (int kb = 0; kb < 8; ++kb) {
            bf16x8v A2[2], B2[2];
#pragma unroll
            for (int i = 0; i < 2; ++i)
                A2[i] = *(const bf16x8v*)&xdT[wm + i * 16 + fr][kb * 32 + kg * 8];
#pragma unroll
            for (int j = 0; j < 2; ++j)
                B2[j] = *(const bf16x8v*)&BT[wn + j * 16 + fr][kb * 32 + kg * 8];
#pragma unroll
            for (int i = 0; i < 2; ++i)
#pragma unroll
                for (int j = 0; j < 2; ++j)
                    acc[i][j] = __builtin_amdgcn_mfma_f32_16x16x32_bf16(
                        A2[i], B2[j], acc[i][j], 0, 0, 0);
        }
#pragma unroll
        for (int i = 0; i < 2; ++i)
#pragma unroll
            for (int j = 0; j < 2; ++j)
#pragma unroll
                for (int rg = 0; rg < 4; ++rg) {
                    int p = wm + i * 16 + kg * 4 + rg;
                    int n = nh * 64 + wn + j * 16 + fr;
                    states[base + (size_t)p * DS + n] = acc[i][j][rg];
                }
    }
}

// ---------------- K5: inter-chunk scan, in place ------------------------------
__global__ __launch_bounds__(256) void chunk_scan_kernel(
    float* __restrict__ states, const float* __restrict__ Ac2) {
    int bh = blockIdx.x;
    int tid = threadIdx.x;
    float carry[32];
#pragma unroll
    for (int j = 0; j < 32; ++j) carry[j] = 0.f;
    for (int c = 0; c < NC; ++c) {
        float dec = exp2f(Ac2[(size_t)bh * LQ + c * CH + (CH - 1)]);
        size_t base = (size_t)(bh * NC + c) * (HD * DS);
#pragma unroll
        for (int j = 0; j < 32; ++j) {
            size_t idx = base + tid + j * 256;
            float tmp = states[idx];
            states[idx] = carry[j];
            carry[j] = carry[j] * dec + tmp;
        }
    }
}

// ---------------- y slab helper: S^T GEMM -> packed P -> P·xdt ---------------
template <int MASKED>
__device__ __forceinline__ void y_slab(
    const bf16* __restrict__ xBC, int rch, int s0, int fr, int kg,
    const float* As_sh, const float* Al, const bf16x8v CA[4][4],
    __bf16 (*Pw)[36], const __bf16 (*xdtT)[264], f32x4v accY[4][4]) {
#pragma unroll
    for (int half = 0; half < 2; ++half) {
        f32x4v Sacc[2][4] = {};
#pragma unroll
        for (int ks = 0; ks < 4; ++ks) {
            bf16x8v SB[2];
#pragma unroll
            for (int st2 = 0; st2 < 2; ++st2)
                SB[st2] = *(const bf16x8v*)&xBC[
                    (size_t)(rch + s0 + half * 32 + st2 * 16 + fr) * XBC_C
                    + DI + ks * 32 + kg * 8];
#pragma unroll
            for (int st2 = 0; st2 < 2; ++st2)
#pragma unroll
                for (int mt = 0; mt < 4; ++mt) {
                    if (MASKED && (half * 2 + st2) > mt) continue;
                    // D[m=s][n=l]: A = B-rows, B = C-rows
                    Sacc[st2][mt] = __builtin_amdgcn_mfma_f32_16x16x32_bf16(
                        SB[st2], CA[mt][ks], Sacc[st2][mt], 0, 0, 0);
                }
        }
#pragma unroll
        for (int st2 = 0; st2 < 2; ++st2) {
            int sblk = half * 2 + st2;
            float4 As4 = *(const float4*)&As_sh[s0 + half * 32 + st2 * 16 + kg * 4];
            float as[4] = {As4.x, As4.y, As4.z, As4.w};
#pragma unroll
            for (int mt = 0; mt < 4; ++mt) {
                bf16x4v pv;
                if (MASKED && sblk > mt) {
                    pv[0] = pv[1] = pv[2] = pv[3] = (__bf16)0.f;
                } else {
#pragma unroll
                    for (int rg = 0; rg < 4; ++rg) {
                        float v = Sacc[st2][mt][rg] * exp2f(Al[mt] - as[rg]);
                        if (MASKED && sblk == mt && (kg * 4 + rg) > fr) v = 0.f;
                        pv[rg] = (__bf16)v;
                    }
                }
                *(bf16x4v*)&Pw[mt * 16 + fr][st2 * 16 + kg * 4] = pv;
            }
        }
        __asm__ volatile("s_waitcnt lgkmcnt(0)" ::: "memory");
        bf16x8v PA[4], XB[4];
#pragma unroll
        for (int mt = 0; mt < 4; ++mt) {
            bf16x4v plo = *(const bf16x4v*)&Pw[mt * 16 + fr][kg * 8];
            bf16x4v phi = *(const bf16x4v*)&Pw[mt * 16 + fr][kg * 8 + 4];
            bf16x8v pa;
#pragma unroll
            for (int j = 0; j < 4; ++j) { pa[j] = plo[j]; pa[4 + j] = phi[j]; }
            PA[mt] = pa;
        }
#pragma unroll
        for (int pt = 0; pt < 4; ++pt)
            XB[pt] = *(const bf16x8v*)&xdtT[pt * 16 + fr][s0 + half * 32 + kg * 8];
#pragma unroll
        for (int mt = 0; mt < 4; ++mt)
#pragma unroll
            for (int pt = 0; pt < 4; ++pt)
                accY[mt][pt] = __builtin_amdgcn_mfma_f32_16x16x32_bf16(
                    PA[mt], XB[pt], accY[mt][pt], 0, 0, 0);
        __asm__ volatile("s_waitcnt lgkmcnt(0)" ::: "memory");
    }
}

// ---------------- K4b (MFMA): Y = (C·B^T ∘ L)·xdt + 2^Ac2·(C·prev^T) ---------
__global__ __launch_bounds__(256) void y_mfma_kernel(
    const bf16* __restrict__ xBC, const float* __restrict__ dt_bh,
    const float* __restrict__ Ac2, const float* __restrict__ prev,
    bf16* __restrict__ yout /* zx+2048, stride ZXS */) {
    __shared__ __align__(16) __bf16 xdtT[64][264];   // [p][s]
    __shared__ __align__(16) __bf16 P[4][64][36];    // per-wave, [l][s-half]
    __shared__ float As_sh[256];
    int bid = blockIdx.x;
    int c = bid & 15, h = (bid >> 4) & 31, b = bid >> 9;
    int bh = b * NH + h;
    int rch = b * LQ + c * CH;
    int tid = threadIdx.x;
    int wave = tid >> 6, lane = tid & 63;
    int fr = lane & 15, kg = lane >> 4;

    As_sh[tid] = Ac2[(size_t)bh * LQ + c * CH + tid];
    {   // xdtT[p][s] = x[s][p] * dt[s]
        int p2 = (tid & 31) * 2;
        int srow = tid >> 5;
#pragma unroll 4
        for (int pass = 0; pass < 32; ++pass) {
            int s = pass * 8 + srow;
            float dtv = dt_bh[(size_t)bh * LQ + c * CH + s];
            __hip_bfloat162 xv =
                *(const __hip_bfloat162*)&xBC[(size_t)(rch + s) * XBC_C + h * HD + p2];
            xdtT[p2][s]     = (__bf16)(__bfloat162float(xv.x) * dtv);
            xdtT[p2 + 1][s] = (__bf16)(__bfloat162float(xv.y) * dtv);
        }
    }
    __syncthreads();

    // cache C A-fragments (rows of C) for this wave's strip: [mt][ks]
    bf16x8v CA[4][4];
    {
        size_t rb = (size_t)(rch + wave * 64 + fr) * XBC_C + DI + DS + kg * 8;
#pragma unroll
        for (int mt = 0; mt < 4; ++mt)
#pragma unroll
            for (int ks = 0; ks < 4; ++ks)
                CA[mt][ks] = *(const bf16x8v*)&xBC[rb + (size_t)mt * 16 * XBC_C + ks * 32];
    }

    f32x4v accY[4][4] = {};    // [mt][pt], D[m=l][n=p]

    // off-diagonal: C · prev^T
    {
        size_t pbase = (size_t)(bh * NC + c) * HD * DS;
#pragma unroll
        for (int ks = 0; ks < 4; ++ks) {
            bf16x8v PB[4];
#pragma unroll
            for (int pt = 0; pt < 4; ++pt) {
                const float* pp = &prev[pbase + (size_t)(pt * 16 + fr) * DS + ks * 32 + kg * 8];
                float4 a4 = *(const float4*)pp;
                float4 b4 = *(const float4*)(pp + 4);
                bf16x8v t;
                t[0] = (__bf16)a4.x; t[1] = (__bf16)a4.y; t[2] = (__bf16)a4.z; t[3] = (__bf16)a4.w;
                t[4] = (__bf16)b4.x; t[5] = (__bf16)b4.y; t[6] = (__bf16)b4.z; t[7] = (__bf16)b4.w;
                PB[pt] = t;
            }
#pragma unroll
            for (int mt = 0; mt < 4; ++mt)
#pragma unroll
                for (int pt = 0; pt < 4; ++pt)
                    accY[mt][pt] = __builtin_amdgcn_mfma_f32_16x16x32_bf16(
                        CA[mt][ks], PB[pt], accY[mt][pt], 0, 0, 0);
        }
    }
    int l0 = wave * 64;
    // scale off-diag by 2^Ac2[l]  (accY row l = l0 + mt*16 + kg*4 + rg)
#pragma unroll
    for (int mt = 0; mt < 4; ++mt) {
#pragma unroll
        for (int rg = 0; rg < 4; ++rg) {
            float e = exp2f(As_sh[l0 + mt * 16 + kg * 4 + rg]);
#pragma unroll
            for (int pt = 0; pt < 4; ++pt)
                accY[mt][pt][rg] *= e;
        }
    }

    // Al per lane (l = l0 + mt*16 + fr), fixed across st-slabs
    float Al[4];
#pragma unroll
    for (int mt = 0; mt < 4; ++mt) Al[mt] = As_sh[l0 + mt * 16 + fr];

    __bf16 (*Pw)[36] = P[wave];
    for (int st = 0; st < wave; ++st)
        y_slab<0>(xBC, rch, st * 64, fr, kg, As_sh, Al, CA, Pw, xdtT, accY);
    y_slab<1>(xBC, rch, l0, fr, kg, As_sh, Al, CA, Pw, xdtT, accY);

    // epilogue: two 32-col passes staged through P for coalesced stores
#pragma unroll
    for (int ph = 0; ph < 2; ++ph) {
#pragma unroll
        for (int mt = 0; mt < 4; ++mt)
#pragma unroll
            for (int ptl = 0; ptl < 2; ++ptl)
#pragma unroll
                for (int rg = 0; rg < 4; ++rg)
                    Pw[mt * 16 + kg * 4 + rg][ptl * 16 + fr] =
                        (__bf16)accY[mt][ph * 2 + ptl][rg];
        __asm__ volatile("s_waitcnt lgkmcnt(0)" ::: "memory");
        bf16* yp = yout + (size_t)(rch + l0 + lane) * ZXS + h * HD + ph * 32;
#pragma unroll
        for (int q = 0; q < 4; ++q) {
            bf16x4v a = *(const bf16x4v*)&Pw[lane][q * 8];
            bf16x4v bq = *(const bf16x4v*)&Pw[lane][q * 8 + 4];
            bf16x8v v;
#pragma unroll
            for (int j = 0; j < 4; ++j) { v[j] = a[j]; v[4 + j] = bq[j]; }
            *(bf16x8v*)(yp + q * 8) = v;
        }
        __asm__ volatile("s_waitcnt lgkmcnt(0)" ::: "memory");
    }
}

// ---------------- F3: gated RMSNorm rows, plus out_proj transpose tiles ------
__global__ __launch_bounds__(256) void fused_gate_trans_kernel(
    const bf16* __restrict__ zx, const float* __restrict__ gw,
    const float* __restrict__ Dvec, const bf16* __restrict__ xBC,
    bf16* __restrict__ y /* zx+2048, lda ZXS */,
    const float* __restrict__ out_proj, bf16* __restrict__ Bt2) {
    int bid = blockIdx.x;
    if (bid < RTOT) {
        int r = bid, tid = threadIdx.x;
        int i0 = tid * 8;
        bf16x8v zv = *(const bf16x8v*)&zx[(size_t)r * ZXS + i0];
        bf16x8v yv = *(const bf16x8v*)&y[(size_t)r * ZXS + i0];
        bf16x8v xv = *(const bf16x8v*)&xBC[(size_t)r * XBC_C + i0];
        float Dh = Dvec[tid >> 3];
        float v[8];
        float ss = 0.f;
#pragma unroll
        for (int j = 0; j < 8; ++j) {
            float z = (float)zv[j];
            float val = ((float)yv[j] + Dh * (float)xv[j]) * (z / (1.f + __expf(-z)));
            v[j] = val;
            ss += val * val;
        }
        ss = block_reduce_sum(ss);
        float scale = rsqrtf(ss / (float)DI + EPS);
        float4 g0 = *(const float4*)&gw[i0];
        float4 g1 = *(const float4*)&gw[i0 + 4];
        float g[8] = {g0.x, g0.y, g0.z, g0.w, g1.x, g1.y, g1.z, g1.w};
        bf16x8v ov;
#pragma unroll
        for (int j = 0; j < 8; ++j)
            ov[j] = (__bf16)(v[j] * scale * g[j]);
        *(bf16x8v*)&y[(size_t)r * ZXS + i0] = ov;
    } else {
        int t = bid - RTOT;                    // [0, 2048)
        transpose_tile(out_proj, Bt2, DI, DM, (t & 31) * 32, (t >> 5) * 32);
    }
}

// ---------------- launch ----------------
extern "C" void kernel_launch(void* const* d_in, const int* in_sizes, int n_in,
                              void* d_out, int out_size, void* d_ws, size_t ws_size,
                              hipStream_t stream) {
    const float* hid      = (const float*)d_in[0];
    const float* resid    = (const float*)d_in[1];
    const float* norm_w   = (const float*)d_in[2];
    const float* in_proj  = (const float*)d_in[3];
    const float* conv_w   = (const float*)d_in[4];
    const float* conv_b   = (const float*)d_in[5];
    const float* dt_bias  = (const float*)d_in[6];
    const float* A_log    = (const float*)d_in[7];
    const float* Dvec     = (const float*)d_in[8];
    const float* gate_w   = (const float*)d_in[9];
    const float* out_proj = (const float*)d_in[10];

    float* out_p   = (float*)d_out;                  // [8192,1024] f32
    float* res_out = out_p + (size_t)RTOT * DM;      // [8192,1024] f32
    bf16*  h_bf16  = (bf16*)out_p;                   // dead after GEMM1
    float* states  = out_p;                          // 33.55 MB exact fit

    char* wsb = (char*)d_ws;
    bf16*  zx      = (bf16*)wsb;  wsb += (size_t)RTOT * ZXS * sizeof(bf16);    // 71.3 MB
    bf16*  xBC     = (bf16*)wsb;  wsb += (size_t)RTOT * XBC_C * sizeof(bf16);  // 37.7 MB
    float* dtraw   = (float*)wsb; wsb += (size_t)RTOT * 32 * sizeof(float);    // 1 MB
    float* dt_bh   = (float*)wsb; wsb += (size_t)BATCH * NH * LQ * sizeof(float);
    float* Ac2_bh  = (float*)wsb; wsb += (size_t)BATCH * NH * LQ * sizeof(float);
    wsb += (size_t)1 << 20;   // Bt2 spillover beyond Ac2 (total ~113.3 MB)
    bf16* Bt1 = xBC;                 // aliases xBC front (dead at that time)
    bf16* Bt2 = (bf16*)dtraw;        // spans dtraw..Ac2+1MB (all dead by F3)

    fused_pre_kernel<<<RTOT + 4480, 256, 0, stream>>>(
        hid, resid, norm_w, res_out, h_bf16, in_proj, Bt1);
    gemm_mfma_kernel<0><<<dim3(NP1 / 128, RTOT / 128), 256, 0, stream>>>(
        h_bf16, DM, Bt1, zx, ZXS, RTOT, ZX_C, DM, dtraw);
    fused_conv_dt_kernel<<<9216 + 1024, 256, 0, stream>>>(
        zx, conv_w, conv_b, xBC, dtraw, dt_bias, A_log, dt_bh, Ac2_bh);
    states_mfma_kernel<<<BATCH * NH * NC, 256, 0, stream>>>(
        xBC, dt_bh, Ac2_bh, states);
    chunk_scan_kernel<<<BATCH * NH, 256, 0, stream>>>(states, Ac2_bh);
    y_mfma_kernel<<<BATCH * NH * NC, 256, 0, stream>>>(
        xBC, dt_bh, Ac2_bh, states, zx + DI);
    fused_gate_trans_kernel<<<RTOT + 2048, 256, 0, stream>>>(
        zx, gate_w, Dvec, xBC, zx + DI, out_proj, Bt2);
    gemm_mfma_kernel<1><<<dim3(DM / 128, RTOT / 128), 256, 0, stream>>>(
        zx + DI, ZXS, Bt2, out_p, DM, RTOT, DM, DI, nullptr);
}